// Round 1
// baseline (777.903 us; speedup 1.0000x reference)
//
#include <hip/hip_runtime.h>
#include <math.h>

#define EPSF 1e-7f
#define MIN_NORM 1e-15f
#define MAXNORM 0.996f   // (1 - 0.004)/sqrt(c), c=1
#define NEG_SLOPE 0.2f

__device__ __forceinline__ float wave_reduce_sum(float v) {
    #pragma unroll
    for (int m = 1; m < 64; m <<= 1) v += __shfl_xor(v, m, 64);
    return v;
}

__device__ __forceinline__ float artanhf_(float x) {
    x = fminf(fmaxf(x, -1.f + EPSF), 1.f - EPSF);
    return 0.5f * (log1pf(x) - log1pf(-x));
}

// monotonic float -> uint mapping for atomicMax
__device__ __forceinline__ unsigned fmap(float f) {
    unsigned u = __float_as_uint(f);
    return (u & 0x80000000u) ? ~u : (u | 0x80000000u);
}
__device__ __forceinline__ float funmap(unsigned u) {
    return __uint_as_float((u & 0x80000000u) ? (u & 0x7FFFFFFFu) : ~u);
}

// ---- K0: hyp bias = proj(expmap0(lin_bias)), store 128 vals + norm^2 at [128]
__global__ void bias_kernel(const float* __restrict__ lin_bias, float* __restrict__ bbuf) {
    int lane = threadIdx.x;
    float u0 = lin_bias[lane], u1 = lin_bias[lane + 64];
    float n2 = wave_reduce_sum(u0 * u0 + u1 * u1);
    float n = fmaxf(sqrtf(n2), MIN_NORM);
    float s = tanhf(n) / n;
    float b0 = s * u0, b1 = s * u1;
    float bn2 = wave_reduce_sum(b0 * b0 + b1 * b1);
    float bn = fmaxf(sqrtf(bn2), MIN_NORM);
    if (bn > MAXNORM) { float f = MAXNORM / bn; b0 *= f; b1 *= f; }
    float fn2 = wave_reduce_sum(b0 * b0 + b1 * b1);
    bbuf[lane] = b0;
    bbuf[lane + 64] = b1;
    if (lane == 0) bbuf[128] = fn2;
}

// ---- init smax (to mapped -inf) and den (to 0)
__global__ void init_kernel(unsigned* __restrict__ smax, float* __restrict__ den, int n) {
    int i = blockIdx.x * blockDim.x + threadIdx.x;
    if (i < n) { smax[i] = 0x007FFFFFu; den[i] = 0.f; }
}

// ---- K1: per-node transform. One wave per node; lane owns dims {lane, lane+64}.
#define DPAD 129
__global__ __launch_bounds__(256) void node_kernel(
    const float* __restrict__ x, const float* __restrict__ W,
    const float* __restrict__ bbuf, const float* __restrict__ att,
    float* __restrict__ log_x, float* __restrict__ s_i, float* __restrict__ s_j, int N)
{
    __shared__ float Ws[128 * DPAD];
    __shared__ float xs[4][128];
    int tid = threadIdx.x;
    for (int i = tid; i < 128 * 128; i += 256) {
        int r = i >> 7, c = i & 127;
        Ws[r * DPAD + c] = W[i];
    }
    __syncthreads();

    int wave = tid >> 6, lane = tid & 63;
    float b0 = bbuf[lane], b1 = bbuf[lane + 64];
    float y2 = bbuf[128];
    // att layout: (H=4, 2*32): att_i = att[h*64 + d], att_j = att[h*64 + 32 + d]
    int hA = lane >> 5, hB = 2 + (lane >> 5);
    int dd = lane & 31;
    float aiA = att[hA * 64 + dd], ajA = att[hA * 64 + 32 + dd];
    float aiB = att[hB * 64 + dd], ajB = att[hB * 64 + 32 + dd];

    for (int n = blockIdx.x * 4 + wave; n < N; n += gridDim.x * 4) {
        float x0 = x[(size_t)n * 128 + lane];
        float x1 = x[(size_t)n * 128 + 64 + lane];
        xs[wave][lane] = x0;
        xs[wave][lane + 64] = x1;   // wave-synchronous: in-order DS pipe
        float acc0 = 0.f, acc1 = 0.f;
        const float* xrow = xs[wave];
        #pragma unroll 8
        for (int k = 0; k < 128; ++k) {
            float xv = xrow[k];
            acc0 = fmaf(xv, Ws[lane * DPAD + k], acc0);
            acc1 = fmaf(xv, Ws[(lane + 64) * DPAD + k], acc1);
        }
        // mobius_matvec
        float xn2 = wave_reduce_sum(x0 * x0 + x1 * x1);
        float mxn2 = wave_reduce_sum(acc0 * acc0 + acc1 * acc1);
        float xn = fmaxf(sqrtf(xn2), MIN_NORM);
        float mxn = fmaxf(sqrtf(mxn2), MIN_NORM);
        float t = tanhf(mxn / xn * artanhf_(xn));
        float scl = t / mxn;
        float r0 = scl * acc0, r1 = scl * acc1;
        if (mxn2 == 0.f) { r0 = 0.f; r1 = 0.f; }
        // proj
        float rn2 = wave_reduce_sum(r0 * r0 + r1 * r1);
        float rn = fmaxf(sqrtf(rn2), MIN_NORM);
        if (rn > MAXNORM) { float f = MAXNORM / rn; r0 *= f; r1 *= f; }
        // mobius_add(h, bias)
        float x2 = wave_reduce_sum(r0 * r0 + r1 * r1);
        float xy = wave_reduce_sum(r0 * b0 + r1 * b1);
        float cA = 1.f + 2.f * xy + y2;
        float cB = 1.f - x2;
        float den = fmaxf(1.f + 2.f * xy + x2 * y2, MIN_NORM);
        float h0 = (cA * r0 + cB * b0) / den;
        float h1 = (cA * r1 + cB * b1) / den;
        // proj
        float hn2 = wave_reduce_sum(h0 * h0 + h1 * h1);
        float hn = fmaxf(sqrtf(hn2), MIN_NORM);
        if (hn > MAXNORM) { float f = MAXNORM / hn; h0 *= f; h1 *= f; }
        // logmap0
        float ln2 = wave_reduce_sum(h0 * h0 + h1 * h1);
        float lnn = fmaxf(sqrtf(ln2), MIN_NORM);
        float ls = artanhf_(lnn) / lnn;
        float l0 = ls * h0, l1 = ls * h1;
        log_x[(size_t)n * 128 + lane] = l0;
        log_x[(size_t)n * 128 + 64 + lane] = l1;
        // per-node attention partials (per 32-lane group = one head)
        float pi = l0 * aiA, pj = l0 * ajA;
        float qi = l1 * aiB, qj = l1 * ajB;
        #pragma unroll
        for (int m = 1; m < 32; m <<= 1) {
            pi += __shfl_xor(pi, m, 64);
            pj += __shfl_xor(pj, m, 64);
            qi += __shfl_xor(qi, m, 64);
            qj += __shfl_xor(qj, m, 64);
        }
        if ((lane & 31) == 0) {
            int g = lane >> 5;
            s_i[(size_t)n * 4 + g] = pi;
            s_j[(size_t)n * 4 + g] = pj;
            s_i[(size_t)n * 4 + 2 + g] = qi;
            s_j[(size_t)n * 4 + 2 + g] = qj;
        }
    }
}

// ---- K2: edge scores + segment max (thread per edge; self-loops appended)
__global__ void edge_score_kernel(
    const int* __restrict__ src, const int* __restrict__ dst, int E, int N,
    const float* __restrict__ s_i, const float* __restrict__ s_j,
    float* __restrict__ alpha, unsigned* __restrict__ smax)
{
    int e = blockIdx.x * blockDim.x + threadIdx.x;
    int Etot = E + N;
    if (e >= Etot) return;
    int s_, d_;
    if (e < E) { s_ = src[e]; d_ = dst[e]; } else { s_ = d_ = e - E; }
    float4 si = *(const float4*)(s_i + (size_t)d_ * 4);
    float4 sj = *(const float4*)(s_j + (size_t)s_ * 4);
    float a0 = si.x + sj.x, a1 = si.y + sj.y, a2 = si.z + sj.z, a3 = si.w + sj.w;
    a0 = a0 < 0.f ? a0 * NEG_SLOPE : a0;
    a1 = a1 < 0.f ? a1 * NEG_SLOPE : a1;
    a2 = a2 < 0.f ? a2 * NEG_SLOPE : a2;
    a3 = a3 < 0.f ? a3 * NEG_SLOPE : a3;
    atomicMax(&smax[(size_t)d_ * 4 + 0], fmap(a0));
    atomicMax(&smax[(size_t)d_ * 4 + 1], fmap(a1));
    atomicMax(&smax[(size_t)d_ * 4 + 2], fmap(a2));
    atomicMax(&smax[(size_t)d_ * 4 + 3], fmap(a3));
    *(float4*)(alpha + (size_t)e * 4) = make_float4(a0, a1, a2, a3);
}

// ---- K3: exp + denominator + weighted message scatter (128 threads per edge)
__global__ __launch_bounds__(256) void edge_aggregate_kernel(
    const int* __restrict__ src, const int* __restrict__ dst, int E, int N,
    const float* __restrict__ alpha, const unsigned* __restrict__ smax,
    const float* __restrict__ log_x, float* __restrict__ den, float* __restrict__ num)
{
    long long idx = (long long)blockIdx.x * blockDim.x + threadIdx.x;
    long long tot = (long long)(E + N) * 128;
    if (idx >= tot) return;
    int e = (int)(idx >> 7);
    int d = (int)(idx & 127);
    int h = d >> 5;
    int s_, d_;
    if (e < E) { s_ = src[e]; d_ = dst[e]; } else { s_ = d_ = e - E; }
    float a = alpha[(size_t)e * 4 + h];
    float m = funmap(smax[(size_t)d_ * 4 + h]);
    float ex = expf(a - m);
    if ((d & 31) == 0) atomicAdd(&den[(size_t)d_ * 4 + h], ex);
    atomicAdd(&num[(size_t)d_ * 128 + d], ex * log_x[(size_t)s_ * 128 + d]);
}

// ---- K4: out = proj(expmap0(relu(num/den + conv_bias)))   (wave per node)
__global__ void finalize_kernel(const float* __restrict__ den,
                                const float* __restrict__ conv_bias,
                                float* __restrict__ out, int N)
{
    int t = blockIdx.x * blockDim.x + threadIdx.x;
    int n = t >> 6, lane = t & 63;
    if (n >= N) return;
    int g = lane >> 5;
    float d0 = fmaxf(den[(size_t)n * 4 + g], MIN_NORM);
    float d1 = fmaxf(den[(size_t)n * 4 + 2 + g], MIN_NORM);
    float v0 = out[(size_t)n * 128 + lane] / d0 + conv_bias[lane];
    float v1 = out[(size_t)n * 128 + 64 + lane] / d1 + conv_bias[lane + 64];
    v0 = fmaxf(v0, 0.f);
    v1 = fmaxf(v1, 0.f);
    float n2 = wave_reduce_sum(v0 * v0 + v1 * v1);
    float nn = fmaxf(sqrtf(n2), MIN_NORM);
    float s = tanhf(nn) / nn;
    float r0 = s * v0, r1 = s * v1;
    float rn2 = wave_reduce_sum(r0 * r0 + r1 * r1);
    float rn = fmaxf(sqrtf(rn2), MIN_NORM);
    if (rn > MAXNORM) { float f = MAXNORM / rn; r0 *= f; r1 *= f; }
    out[(size_t)n * 128 + lane] = r0;
    out[(size_t)n * 128 + 64 + lane] = r1;
}

extern "C" void kernel_launch(void* const* d_in, const int* in_sizes, int n_in,
                              void* d_out, int out_size, void* d_ws, size_t ws_size,
                              hipStream_t stream)
{
    const float* x        = (const float*)d_in[0];
    const float* W        = (const float*)d_in[1];
    const float* lin_bias = (const float*)d_in[2];
    const float* att      = (const float*)d_in[3];
    const float* conv_bias= (const float*)d_in[4];
    const int*   esrc     = (const int*)d_in[5];
    const int*   edst     = (const int*)d_in[6];
    int N = in_sizes[0] / 128;
    int E = in_sizes[5];
    int Etot = E + N;
    float* out = (float*)d_out;

    char* p = (char*)d_ws;
    float*    bbuf  = (float*)p;    p += 256 * 4;
    float*    log_x = (float*)p;    p += (size_t)N * 128 * 4;
    float*    s_i   = (float*)p;    p += (size_t)N * 4 * 4;
    float*    s_j   = (float*)p;    p += (size_t)N * 4 * 4;
    float*    alpha = (float*)p;    p += (size_t)Etot * 4 * 4;
    unsigned* smax  = (unsigned*)p; p += (size_t)N * 4 * 4;
    float*    den   = (float*)p;    p += (size_t)N * 4 * 4;

    hipMemsetAsync(d_out, 0, (size_t)out_size * sizeof(float), stream);
    bias_kernel<<<1, 64, 0, stream>>>(lin_bias, bbuf);
    init_kernel<<<(N * 4 + 255) / 256, 256, 0, stream>>>(smax, den, N * 4);
    node_kernel<<<512, 256, 0, stream>>>(x, W, bbuf, att, log_x, s_i, s_j, N);
    edge_score_kernel<<<(Etot + 255) / 256, 256, 0, stream>>>(esrc, edst, E, N, s_i, s_j, alpha, smax);
    long long tot = (long long)Etot * 128;
    edge_aggregate_kernel<<<(int)((tot + 255) / 256), 256, 0, stream>>>(
        esrc, edst, E, N, alpha, smax, log_x, den, out);
    finalize_kernel<<<(N * 64 + 255) / 256, 256, 0, stream>>>(den, conv_bias, out, N);
}

// Round 2
// 389.830 us; speedup vs baseline: 1.9955x; 1.9955x over previous
//
#include <hip/hip_runtime.h>
#include <math.h>

#define EPSF 1e-7f
#define MIN_NORM 1e-15f
#define MAXNORM 0.996f   // (1 - 0.004)/sqrt(c), c=1
#define NEG_SLOPE 0.2f

__device__ __forceinline__ float wave_reduce_sum(float v) {
    #pragma unroll
    for (int m = 1; m < 64; m <<= 1) v += __shfl_xor(v, m, 64);
    return v;
}

__device__ __forceinline__ float artanhf_(float x) {
    x = fminf(fmaxf(x, -1.f + EPSF), 1.f - EPSF);
    return 0.5f * (log1pf(x) - log1pf(-x));
}

__device__ __forceinline__ float lrelu(float a) {
    return a < 0.f ? a * NEG_SLOPE : a;
}

// ---- K0: hyp bias = proj(expmap0(lin_bias)), store 128 vals + norm^2 at [128]
__global__ void bias_kernel(const float* __restrict__ lin_bias, float* __restrict__ bbuf) {
    int lane = threadIdx.x;
    float u0 = lin_bias[lane], u1 = lin_bias[lane + 64];
    float n2 = wave_reduce_sum(u0 * u0 + u1 * u1);
    float n = fmaxf(sqrtf(n2), MIN_NORM);
    float s = tanhf(n) / n;
    float b0 = s * u0, b1 = s * u1;
    float bn2 = wave_reduce_sum(b0 * b0 + b1 * b1);
    float bn = fmaxf(sqrtf(bn2), MIN_NORM);
    if (bn > MAXNORM) { float f = MAXNORM / bn; b0 *= f; b1 *= f; }
    float fn2 = wave_reduce_sum(b0 * b0 + b1 * b1);
    bbuf[lane] = b0;
    bbuf[lane + 64] = b1;
    if (lane == 0) bbuf[128] = fn2;
}

// ---- K1: per-node transform. One wave per node; lane owns dims {lane, lane+64}.
#define DPAD 129
__global__ __launch_bounds__(256) void node_kernel(
    const float* __restrict__ x, const float* __restrict__ W,
    const float* __restrict__ bbuf, const float* __restrict__ att,
    float* __restrict__ log_x, float* __restrict__ s_i, float* __restrict__ s_j, int N)
{
    __shared__ float Ws[128 * DPAD];
    __shared__ float xs[4][128];
    int tid = threadIdx.x;
    for (int i = tid; i < 128 * 128; i += 256) {
        int r = i >> 7, c = i & 127;
        Ws[r * DPAD + c] = W[i];
    }
    __syncthreads();

    int wave = tid >> 6, lane = tid & 63;
    float b0 = bbuf[lane], b1 = bbuf[lane + 64];
    float y2 = bbuf[128];
    int hA = lane >> 5, hB = 2 + (lane >> 5);
    int dd = lane & 31;
    float aiA = att[hA * 64 + dd], ajA = att[hA * 64 + 32 + dd];
    float aiB = att[hB * 64 + dd], ajB = att[hB * 64 + 32 + dd];

    for (int n = blockIdx.x * 4 + wave; n < N; n += gridDim.x * 4) {
        float x0 = x[(size_t)n * 128 + lane];
        float x1 = x[(size_t)n * 128 + 64 + lane];
        xs[wave][lane] = x0;
        xs[wave][lane + 64] = x1;   // wave-synchronous: in-order DS pipe
        float acc0 = 0.f, acc1 = 0.f;
        const float* xrow = xs[wave];
        #pragma unroll 8
        for (int k = 0; k < 128; ++k) {
            float xv = xrow[k];
            acc0 = fmaf(xv, Ws[lane * DPAD + k], acc0);
            acc1 = fmaf(xv, Ws[(lane + 64) * DPAD + k], acc1);
        }
        // mobius_matvec
        float xn2 = wave_reduce_sum(x0 * x0 + x1 * x1);
        float mxn2 = wave_reduce_sum(acc0 * acc0 + acc1 * acc1);
        float xn = fmaxf(sqrtf(xn2), MIN_NORM);
        float mxn = fmaxf(sqrtf(mxn2), MIN_NORM);
        float t = tanhf(mxn / xn * artanhf_(xn));
        float scl = t / mxn;
        float r0 = scl * acc0, r1 = scl * acc1;
        if (mxn2 == 0.f) { r0 = 0.f; r1 = 0.f; }
        // proj
        float rn2 = wave_reduce_sum(r0 * r0 + r1 * r1);
        float rn = fmaxf(sqrtf(rn2), MIN_NORM);
        if (rn > MAXNORM) { float f = MAXNORM / rn; r0 *= f; r1 *= f; }
        // mobius_add(h, bias)
        float x2 = wave_reduce_sum(r0 * r0 + r1 * r1);
        float xy = wave_reduce_sum(r0 * b0 + r1 * b1);
        float cA = 1.f + 2.f * xy + y2;
        float cB = 1.f - x2;
        float den = fmaxf(1.f + 2.f * xy + x2 * y2, MIN_NORM);
        float h0 = (cA * r0 + cB * b0) / den;
        float h1 = (cA * r1 + cB * b1) / den;
        // proj
        float hn2 = wave_reduce_sum(h0 * h0 + h1 * h1);
        float hn = fmaxf(sqrtf(hn2), MIN_NORM);
        if (hn > MAXNORM) { float f = MAXNORM / hn; h0 *= f; h1 *= f; }
        // logmap0
        float ln2 = wave_reduce_sum(h0 * h0 + h1 * h1);
        float lnn = fmaxf(sqrtf(ln2), MIN_NORM);
        float ls = artanhf_(lnn) / lnn;
        float l0 = ls * h0, l1 = ls * h1;
        log_x[(size_t)n * 128 + lane] = l0;
        log_x[(size_t)n * 128 + 64 + lane] = l1;
        // per-node attention partials (per 32-lane group = one head)
        float pi = l0 * aiA, pj = l0 * ajA;
        float qi = l1 * aiB, qj = l1 * ajB;
        #pragma unroll
        for (int m = 1; m < 32; m <<= 1) {
            pi += __shfl_xor(pi, m, 64);
            pj += __shfl_xor(pj, m, 64);
            qi += __shfl_xor(qi, m, 64);
            qj += __shfl_xor(qj, m, 64);
        }
        if ((lane & 31) == 0) {
            int g = lane >> 5;
            s_i[(size_t)n * 4 + g] = pi;
            s_j[(size_t)n * 4 + g] = pj;
            s_i[(size_t)n * 4 + 2 + g] = qi;
            s_j[(size_t)n * 4 + 2 + g] = qj;
        }
    }
}

// ---- K2: per-dst in-degree count (real edges only; self-loops handled analytically)
__global__ void count_kernel(const int* __restrict__ dst, int E, int* __restrict__ cnt) {
    int e = blockIdx.x * blockDim.x + threadIdx.x;
    if (e < E) atomicAdd(&cnt[dst[e]], 1);
}

// ---- K3: exclusive scan of cnt -> rowptr (single block, 1024 threads)
__global__ __launch_bounds__(1024) void scan_kernel(const int* __restrict__ cnt,
                                                    int* __restrict__ rowptr, int N) {
    __shared__ int part[1024];
    int t = threadIdx.x;
    int chunk = (N + 1023) / 1024;
    int lo = t * chunk, hi = min(lo + chunk, N);
    int s = 0;
    for (int i = lo; i < hi; ++i) s += cnt[i];
    part[t] = s;
    __syncthreads();
    for (int off = 1; off < 1024; off <<= 1) {
        int v = (t >= off) ? part[t - off] : 0;
        __syncthreads();
        part[t] += v;
        __syncthreads();
    }
    int run = (t == 0) ? 0 : part[t - 1];
    for (int i = lo; i < hi; ++i) { rowptr[i] = run; run += cnt[i]; }
    if (t == 0) rowptr[N] = part[1023];
}

// ---- K4: fill CSR with src id + leakyrelu'd 4-head alpha
__global__ void fill_kernel(const int* __restrict__ src, const int* __restrict__ dst, int E,
                            const float* __restrict__ s_i, const float* __restrict__ s_j,
                            const int* __restrict__ rowptr, int* __restrict__ cursor,
                            int* __restrict__ csr_src, float* __restrict__ csr_alpha)
{
    int e = blockIdx.x * blockDim.x + threadIdx.x;
    if (e >= E) return;
    int s_ = src[e], d_ = dst[e];
    float4 si = *(const float4*)(s_i + (size_t)d_ * 4);
    float4 sj = *(const float4*)(s_j + (size_t)s_ * 4);
    float4 a = make_float4(lrelu(si.x + sj.x), lrelu(si.y + sj.y),
                           lrelu(si.z + sj.z), lrelu(si.w + sj.w));
    int pos = rowptr[d_] + atomicAdd(&cursor[d_], 1);
    csr_src[pos] = s_;
    *(float4*)(csr_alpha + (size_t)pos * 4) = a;
}

// ---- K5: per-node segment softmax + weighted gather + finalize. One wave/node.
__global__ __launch_bounds__(256) void aggregate_kernel(
    const int* __restrict__ rowptr, const int* __restrict__ csr_src,
    const float* __restrict__ csr_alpha,
    const float* __restrict__ s_i, const float* __restrict__ s_j,
    const float* __restrict__ log_x, const float* __restrict__ conv_bias,
    float* __restrict__ out, int N)
{
    int t = blockIdx.x * blockDim.x + threadIdx.x;
    int n = t >> 6, lane = t & 63;
    if (n >= N) return;
    int base = rowptr[n];
    int deg = rowptr[n + 1] - base;

    float4 si = *(const float4*)(s_i + (size_t)n * 4);
    float4 sj = *(const float4*)(s_j + (size_t)n * 4);
    float as0 = lrelu(si.x + sj.x), as1 = lrelu(si.y + sj.y);
    float as2 = lrelu(si.z + sj.z), as3 = lrelu(si.w + sj.w);

    int hm = lane & 3;
    float a_self_h = hm == 0 ? as0 : (hm == 1 ? as1 : (hm == 2 ? as2 : as3));

    // Phase A: per-head max over {self} ∪ edge list. csr_alpha[base*4 + k]: k&3 == hm.
    const float* abase = csr_alpha + (size_t)base * 4;
    float mx = a_self_h;
    for (int k = lane; k < deg * 4; k += 64) mx = fmaxf(mx, abase[k]);
    #pragma unroll
    for (int m = 4; m < 64; m <<= 1) mx = fmaxf(mx, __shfl_xor(mx, m, 64));

    // Phase B: per-head denominator
    float dn = (lane < 4) ? __expf(a_self_h - mx) : 0.f;
    for (int k = lane; k < deg * 4; k += 64) dn += __expf(abase[k] - mx);
    #pragma unroll
    for (int m = 4; m < 64; m <<= 1) dn += __shfl_xor(dn, m, 64);

    float mx0 = __shfl(mx, 0, 64), mx1 = __shfl(mx, 1, 64);
    float mx2 = __shfl(mx, 2, 64), mx3 = __shfl(mx, 3, 64);
    float dn0 = __shfl(dn, 0, 64), dn1 = __shfl(dn, 1, 64);
    float dn2 = __shfl(dn, 2, 64), dn3 = __shfl(dn, 3, 64);

    int g = lane >> 5;                // dim lane -> head g; dim lane+64 -> head 2+g
    float mxa = g == 0 ? mx0 : mx1, mxb = g == 0 ? mx2 : mx3;
    float dna = g == 0 ? dn0 : dn1, dnb = g == 0 ? dn2 : dn3;
    float asa = g == 0 ? as0 : as1, asb = g == 0 ? as2 : as3;

    // Phase C: weighted message accumulation (self + edges)
    float acc0 = __expf(asa - mxa) * log_x[(size_t)n * 128 + lane];
    float acc1 = __expf(asb - mxb) * log_x[(size_t)n * 128 + 64 + lane];
    int sNext = deg > 0 ? csr_src[base] : 0;
    for (int i = 0; i < deg; ++i) {
        int s_ = sNext;
        if (i + 1 < deg) sNext = csr_src[base + i + 1];
        float a0 = abase[(size_t)i * 4 + g];
        float a1 = abase[(size_t)i * 4 + 2 + g];
        float e0 = __expf(a0 - mxa), e1 = __expf(a1 - mxb);
        acc0 = fmaf(e0, log_x[(size_t)s_ * 128 + lane], acc0);
        acc1 = fmaf(e1, log_x[(size_t)s_ * 128 + 64 + lane], acc1);
    }

    // finalize: relu(num/den + bias) -> expmap0 -> proj
    float v0 = acc0 / fmaxf(dna, MIN_NORM) + conv_bias[lane];
    float v1 = acc1 / fmaxf(dnb, MIN_NORM) + conv_bias[lane + 64];
    v0 = fmaxf(v0, 0.f);
    v1 = fmaxf(v1, 0.f);
    float n2 = wave_reduce_sum(v0 * v0 + v1 * v1);
    float nn = fmaxf(sqrtf(n2), MIN_NORM);
    float s = tanhf(nn) / nn;
    float r0 = s * v0, r1 = s * v1;
    float rn2 = wave_reduce_sum(r0 * r0 + r1 * r1);
    float rn = fmaxf(sqrtf(rn2), MIN_NORM);
    if (rn > MAXNORM) { float f = MAXNORM / rn; r0 *= f; r1 *= f; }
    out[(size_t)n * 128 + lane] = r0;
    out[(size_t)n * 128 + 64 + lane] = r1;
}

extern "C" void kernel_launch(void* const* d_in, const int* in_sizes, int n_in,
                              void* d_out, int out_size, void* d_ws, size_t ws_size,
                              hipStream_t stream)
{
    const float* x        = (const float*)d_in[0];
    const float* W        = (const float*)d_in[1];
    const float* lin_bias = (const float*)d_in[2];
    const float* att      = (const float*)d_in[3];
    const float* conv_bias= (const float*)d_in[4];
    const int*   esrc     = (const int*)d_in[5];
    const int*   edst     = (const int*)d_in[6];
    int N = in_sizes[0] / 128;
    int E = in_sizes[5];
    float* out = (float*)d_out;

    char* p = (char*)d_ws;
    float* bbuf   = (float*)p;  p += 256 * 4;
    float* log_x  = (float*)p;  p += (size_t)N * 128 * 4;
    float* s_i    = (float*)p;  p += (size_t)N * 4 * 4;
    float* s_j    = (float*)p;  p += (size_t)N * 4 * 4;
    int*   cnt    = (int*)p;    p += (size_t)N * 4;
    int*   cursor = (int*)p;    p += (size_t)N * 4;
    int*   rowptr = (int*)p;    p += (size_t)(N + 1) * 4;
    int*   csr_src= (int*)p;    p += (size_t)E * 4;
    float* csr_alpha = (float*)p; p += (size_t)E * 4 * 4;

    // zero cnt + cursor (adjacent) in one async memset
    hipMemsetAsync(cnt, 0, (size_t)N * 2 * 4, stream);

    bias_kernel<<<1, 64, 0, stream>>>(lin_bias, bbuf);
    count_kernel<<<(E + 255) / 256, 256, 0, stream>>>(edst, E, cnt);
    scan_kernel<<<1, 1024, 0, stream>>>(cnt, rowptr, N);
    node_kernel<<<512, 256, 0, stream>>>(x, W, bbuf, att, log_x, s_i, s_j, N);
    fill_kernel<<<(E + 255) / 256, 256, 0, stream>>>(esrc, edst, E, s_i, s_j,
                                                     rowptr, cursor, csr_src, csr_alpha);
    aggregate_kernel<<<(N * 64 + 255) / 256, 256, 0, stream>>>(
        rowptr, csr_src, csr_alpha, s_i, s_j, log_x, conv_bias, out, N);
}

// Round 3
// 316.009 us; speedup vs baseline: 2.4617x; 1.2336x over previous
//
#include <hip/hip_runtime.h>
#include <math.h>

#define EPSF 1e-7f
#define MIN_NORM 1e-15f
#define MAXNORM 0.996f   // (1 - 0.004)/sqrt(c), c=1
#define NEG_SLOPE 0.2f

typedef __attribute__((ext_vector_type(8))) short short8;
typedef __attribute__((ext_vector_type(4))) float f32x4;

__device__ __forceinline__ float wave_reduce_sum(float v) {
    #pragma unroll
    for (int m = 1; m < 64; m <<= 1) v += __shfl_xor(v, m, 64);
    return v;
}

__device__ __forceinline__ float artanhf_(float x) {
    x = fminf(fmaxf(x, -1.f + EPSF), 1.f - EPSF);
    return 0.5f * (log1pf(x) - log1pf(-x));
}

__device__ __forceinline__ float lrelu(float a) {
    return a < 0.f ? a * NEG_SLOPE : a;
}

// bf16 round-to-nearest-even (no NaN handling; inputs are tame)
__device__ __forceinline__ unsigned short f2bf(float f) {
    unsigned u = __float_as_uint(f);
    u += 0x7FFFu + ((u >> 16) & 1u);
    return (unsigned short)(u >> 16);
}
__device__ __forceinline__ float bf2f(unsigned short h) {
    return __uint_as_float(((unsigned)h) << 16);
}

// ---- K0: hyp bias = proj(expmap0(lin_bias)), store 128 vals + norm^2 at [128]
__global__ void bias_kernel(const float* __restrict__ lin_bias, float* __restrict__ bbuf) {
    int lane = threadIdx.x;
    float u0 = lin_bias[lane], u1 = lin_bias[lane + 64];
    float n2 = wave_reduce_sum(u0 * u0 + u1 * u1);
    float n = fmaxf(sqrtf(n2), MIN_NORM);
    float s = tanhf(n) / n;
    float b0 = s * u0, b1 = s * u1;
    float bn2 = wave_reduce_sum(b0 * b0 + b1 * b1);
    float bn = fmaxf(sqrtf(bn2), MIN_NORM);
    if (bn > MAXNORM) { float f = MAXNORM / bn; b0 *= f; b1 *= f; }
    float fn2 = wave_reduce_sum(b0 * b0 + b1 * b1);
    bbuf[lane] = b0;
    bbuf[lane + 64] = b1;
    if (lane == 0) bbuf[128] = fn2;
}

// ---- Kw: split W into bf16 hi/lo in B-fragment order.
// Fragment element for out-tile t (0..7), k-step s (0..3), lane l, idx i:
//   B[k][j]: j = l&15 -> out dim o = t*16+j ; k = s*32 + (l>>4)*8 + i
//   stored flat at (((t*4+s)*64)+l)*8 + i
__global__ void wsplit_kernel(const float* __restrict__ W,
                              unsigned short* __restrict__ whi,
                              unsigned short* __restrict__ wlo) {
    int idx = blockIdx.x * 256 + threadIdx.x;   // 0..16383
    int i = idx & 7, l = (idx >> 3) & 63, ts = idx >> 9;
    int s = ts & 3, t = ts >> 2;
    int o = t * 16 + (l & 15);
    int k = s * 32 + ((l >> 4) * 8) + i;
    float f = W[o * 128 + k];
    unsigned short h = f2bf(f);
    unsigned short lo = f2bf(f - bf2f(h));
    whi[idx] = h;
    wlo[idx] = lo;
}

// ---- K1: per-node transform, MFMA matvec (bf16x3) + hyperbolic chain.
// 256 threads = 4 waves; block handles 16 nodes.
#define DPAD 129
__global__ __launch_bounds__(256) void node_kernel(
    const float* __restrict__ x,
    const unsigned short* __restrict__ whi, const unsigned short* __restrict__ wlo,
    const float* __restrict__ bbuf, const float* __restrict__ att,
    float* __restrict__ log_x, float* __restrict__ s_i, float* __restrict__ s_j, int N)
{
    __shared__ float mxs[16][DPAD];
    int tid = threadIdx.x, wave = tid >> 6, lane = tid & 63;
    int nbase = blockIdx.x * 16;
    int arow = lane & 15, kgrp = lane >> 4;
    int anode = min(nbase + arow, N - 1);

    f32x4 acc0 = {0.f, 0.f, 0.f, 0.f};
    f32x4 acc1 = {0.f, 0.f, 0.f, 0.f};
    int t0 = wave * 2, t1 = wave * 2 + 1;

    #pragma unroll
    for (int s = 0; s < 4; ++s) {
        const float* xp = x + (size_t)anode * 128 + s * 32 + kgrp * 8;
        float4 xa = *(const float4*)xp;
        float4 xb = *(const float4*)(xp + 4);
        float xv[8] = {xa.x, xa.y, xa.z, xa.w, xb.x, xb.y, xb.z, xb.w};
        short8 ahi, alo;
        #pragma unroll
        for (int i = 0; i < 8; ++i) {
            unsigned short h = f2bf(xv[i]);
            unsigned short l = f2bf(xv[i] - bf2f(h));
            ahi[i] = (short)h;
            alo[i] = (short)l;
        }
        short8 bh0 = *(const short8*)(whi + ((size_t)(t0 * 4 + s) * 64 + lane) * 8);
        short8 bl0 = *(const short8*)(wlo + ((size_t)(t0 * 4 + s) * 64 + lane) * 8);
        short8 bh1 = *(const short8*)(whi + ((size_t)(t1 * 4 + s) * 64 + lane) * 8);
        short8 bl1 = *(const short8*)(wlo + ((size_t)(t1 * 4 + s) * 64 + lane) * 8);
        acc0 = __builtin_amdgcn_mfma_f32_16x16x32_bf16(ahi, bh0, acc0, 0, 0, 0);
        acc0 = __builtin_amdgcn_mfma_f32_16x16x32_bf16(alo, bh0, acc0, 0, 0, 0);
        acc0 = __builtin_amdgcn_mfma_f32_16x16x32_bf16(ahi, bl0, acc0, 0, 0, 0);
        acc1 = __builtin_amdgcn_mfma_f32_16x16x32_bf16(ahi, bh1, acc1, 0, 0, 0);
        acc1 = __builtin_amdgcn_mfma_f32_16x16x32_bf16(alo, bh1, acc1, 0, 0, 0);
        acc1 = __builtin_amdgcn_mfma_f32_16x16x32_bf16(ahi, bl1, acc1, 0, 0, 0);
    }
    // D layout: col = lane&15 (out dim within tile), row = (lane>>4)*4 + r (node)
    #pragma unroll
    for (int r = 0; r < 4; ++r) {
        mxs[kgrp * 4 + r][t0 * 16 + arow] = acc0[r];
        mxs[kgrp * 4 + r][t1 * 16 + arow] = acc1[r];
    }
    __syncthreads();

    float b0 = bbuf[lane], b1 = bbuf[lane + 64];
    float y2 = bbuf[128];
    int hA = lane >> 5, dd = lane & 31;
    float aiA = att[hA * 64 + dd], ajA = att[hA * 64 + 32 + dd];
    float aiB = att[(2 + hA) * 64 + dd], ajB = att[(2 + hA) * 64 + 32 + dd];

    for (int i = 0; i < 4; ++i) {
        int nn = wave * 4 + i;
        int node = nbase + nn;
        if (node >= N) break;
        float x0 = x[(size_t)node * 128 + lane];
        float x1 = x[(size_t)node * 128 + 64 + lane];
        float acc0s = mxs[nn][lane];
        float acc1s = mxs[nn][64 + lane];
        // mobius_matvec
        float xn2 = wave_reduce_sum(x0 * x0 + x1 * x1);
        float mxn2 = wave_reduce_sum(acc0s * acc0s + acc1s * acc1s);
        float xn = fmaxf(sqrtf(xn2), MIN_NORM);
        float mxn = fmaxf(sqrtf(mxn2), MIN_NORM);
        float t = tanhf(mxn / xn * artanhf_(xn));
        float scl = t / mxn;
        float r0 = scl * acc0s, r1 = scl * acc1s;
        if (mxn2 == 0.f) { r0 = 0.f; r1 = 0.f; }
        // proj
        float rn2 = wave_reduce_sum(r0 * r0 + r1 * r1);
        float rn = fmaxf(sqrtf(rn2), MIN_NORM);
        if (rn > MAXNORM) { float f = MAXNORM / rn; r0 *= f; r1 *= f; }
        // mobius_add(h, bias)
        float x2 = wave_reduce_sum(r0 * r0 + r1 * r1);
        float xy = wave_reduce_sum(r0 * b0 + r1 * b1);
        float cA = 1.f + 2.f * xy + y2;
        float cB = 1.f - x2;
        float den = fmaxf(1.f + 2.f * xy + x2 * y2, MIN_NORM);
        float h0 = (cA * r0 + cB * b0) / den;
        float h1 = (cA * r1 + cB * b1) / den;
        // proj
        float hn2 = wave_reduce_sum(h0 * h0 + h1 * h1);
        float hn = fmaxf(sqrtf(hn2), MIN_NORM);
        if (hn > MAXNORM) { float f = MAXNORM / hn; h0 *= f; h1 *= f; }
        // logmap0
        float ln2 = wave_reduce_sum(h0 * h0 + h1 * h1);
        float lnn = fmaxf(sqrtf(ln2), MIN_NORM);
        float ls = artanhf_(lnn) / lnn;
        float l0 = ls * h0, l1 = ls * h1;
        log_x[(size_t)node * 128 + lane] = l0;
        log_x[(size_t)node * 128 + 64 + lane] = l1;
        // attention partials per 32-lane head group
        float pi = l0 * aiA, pj = l0 * ajA;
        float qi = l1 * aiB, qj = l1 * ajB;
        #pragma unroll
        for (int m = 1; m < 32; m <<= 1) {
            pi += __shfl_xor(pi, m, 64);
            pj += __shfl_xor(pj, m, 64);
            qi += __shfl_xor(qi, m, 64);
            qj += __shfl_xor(qj, m, 64);
        }
        if ((lane & 31) == 0) {
            int g = lane >> 5;
            s_i[(size_t)node * 4 + g] = pi;
            s_j[(size_t)node * 4 + g] = pj;
            s_i[(size_t)node * 4 + 2 + g] = qi;
            s_j[(size_t)node * 4 + 2 + g] = qj;
        }
    }
}

// ---- K2: per-dst in-degree count (real edges only; self-loops handled analytically)
__global__ void count_kernel(const int* __restrict__ dst, int E, int* __restrict__ cnt) {
    int e = blockIdx.x * blockDim.x + threadIdx.x;
    if (e < E) atomicAdd(&cnt[dst[e]], 1);
}

// ---- K3: exclusive scan of cnt -> rowptr (single block, 1024 threads)
__global__ __launch_bounds__(1024) void scan_kernel(const int* __restrict__ cnt,
                                                    int* __restrict__ rowptr, int N) {
    __shared__ int part[1024];
    int t = threadIdx.x;
    int chunk = (N + 1023) / 1024;
    int lo = t * chunk, hi = min(lo + chunk, N);
    int s = 0;
    for (int i = lo; i < hi; ++i) s += cnt[i];
    part[t] = s;
    __syncthreads();
    for (int off = 1; off < 1024; off <<= 1) {
        int v = (t >= off) ? part[t - off] : 0;
        __syncthreads();
        part[t] += v;
        __syncthreads();
    }
    int run = (t == 0) ? 0 : part[t - 1];
    for (int i = lo; i < hi; ++i) { rowptr[i] = run; run += cnt[i]; }
    if (t == 0) rowptr[N] = part[1023];
}

// ---- K4: fill CSR with src id + leakyrelu'd 4-head alpha
__global__ void fill_kernel(const int* __restrict__ src, const int* __restrict__ dst, int E,
                            const float* __restrict__ s_i, const float* __restrict__ s_j,
                            const int* __restrict__ rowptr, int* __restrict__ cursor,
                            int* __restrict__ csr_src, float* __restrict__ csr_alpha)
{
    int e = blockIdx.x * blockDim.x + threadIdx.x;
    if (e >= E) return;
    int s_ = src[e], d_ = dst[e];
    float4 si = *(const float4*)(s_i + (size_t)d_ * 4);
    float4 sj = *(const float4*)(s_j + (size_t)s_ * 4);
    float4 a = make_float4(lrelu(si.x + sj.x), lrelu(si.y + sj.y),
                           lrelu(si.z + sj.z), lrelu(si.w + sj.w));
    int pos = rowptr[d_] + atomicAdd(&cursor[d_], 1);
    csr_src[pos] = s_;
    *(float4*)(csr_alpha + (size_t)pos * 4) = a;
}

// ---- K5: per-node segment softmax + weighted gather + finalize. One wave/node.
__global__ __launch_bounds__(256) void aggregate_kernel(
    const int* __restrict__ rowptr, const int* __restrict__ csr_src,
    const float* __restrict__ csr_alpha,
    const float* __restrict__ s_i, const float* __restrict__ s_j,
    const float* __restrict__ log_x, const float* __restrict__ conv_bias,
    float* __restrict__ out, int N)
{
    int t = blockIdx.x * blockDim.x + threadIdx.x;
    int n = t >> 6, lane = t & 63;
    if (n >= N) return;
    int base = rowptr[n];
    int deg = rowptr[n + 1] - base;

    float4 si = *(const float4*)(s_i + (size_t)n * 4);
    float4 sj = *(const float4*)(s_j + (size_t)n * 4);
    float as0 = lrelu(si.x + sj.x), as1 = lrelu(si.y + sj.y);
    float as2 = lrelu(si.z + sj.z), as3 = lrelu(si.w + sj.w);

    int hm = lane & 3;
    float a_self_h = hm == 0 ? as0 : (hm == 1 ? as1 : (hm == 2 ? as2 : as3));

    const float* abase = csr_alpha + (size_t)base * 4;
    float mx = a_self_h;
    for (int k = lane; k < deg * 4; k += 64) mx = fmaxf(mx, abase[k]);
    #pragma unroll
    for (int m = 4; m < 64; m <<= 1) mx = fmaxf(mx, __shfl_xor(mx, m, 64));

    float dn = (lane < 4) ? __expf(a_self_h - mx) : 0.f;
    for (int k = lane; k < deg * 4; k += 64) dn += __expf(abase[k] - mx);
    #pragma unroll
    for (int m = 4; m < 64; m <<= 1) dn += __shfl_xor(dn, m, 64);

    float mx0 = __shfl(mx, 0, 64), mx1 = __shfl(mx, 1, 64);
    float mx2 = __shfl(mx, 2, 64), mx3 = __shfl(mx, 3, 64);
    float dn0 = __shfl(dn, 0, 64), dn1 = __shfl(dn, 1, 64);
    float dn2 = __shfl(dn, 2, 64), dn3 = __shfl(dn, 3, 64);

    int g = lane >> 5;
    float mxa = g == 0 ? mx0 : mx1, mxb = g == 0 ? mx2 : mx3;
    float dna = g == 0 ? dn0 : dn1, dnb = g == 0 ? dn2 : dn3;
    float asa = g == 0 ? as0 : as1, asb = g == 0 ? as2 : as3;

    float acc0 = __expf(asa - mxa) * log_x[(size_t)n * 128 + lane];
    float acc1 = __expf(asb - mxb) * log_x[(size_t)n * 128 + 64 + lane];
    int sNext = deg > 0 ? csr_src[base] : 0;
    for (int i = 0; i < deg; ++i) {
        int s_ = sNext;
        if (i + 1 < deg) sNext = csr_src[base + i + 1];
        float a0 = abase[(size_t)i * 4 + g];
        float a1 = abase[(size_t)i * 4 + 2 + g];
        float e0 = __expf(a0 - mxa), e1 = __expf(a1 - mxb);
        acc0 = fmaf(e0, log_x[(size_t)s_ * 128 + lane], acc0);
        acc1 = fmaf(e1, log_x[(size_t)s_ * 128 + 64 + lane], acc1);
    }

    float v0 = acc0 / fmaxf(dna, MIN_NORM) + conv_bias[lane];
    float v1 = acc1 / fmaxf(dnb, MIN_NORM) + conv_bias[lane + 64];
    v0 = fmaxf(v0, 0.f);
    v1 = fmaxf(v1, 0.f);
    float n2 = wave_reduce_sum(v0 * v0 + v1 * v1);
    float nn = fmaxf(sqrtf(n2), MIN_NORM);
    float s = tanhf(nn) / nn;
    float r0 = s * v0, r1 = s * v1;
    float rn2 = wave_reduce_sum(r0 * r0 + r1 * r1);
    float rn = fmaxf(sqrtf(rn2), MIN_NORM);
    if (rn > MAXNORM) { float f = MAXNORM / rn; r0 *= f; r1 *= f; }
    out[(size_t)n * 128 + lane] = r0;
    out[(size_t)n * 128 + 64 + lane] = r1;
}

extern "C" void kernel_launch(void* const* d_in, const int* in_sizes, int n_in,
                              void* d_out, int out_size, void* d_ws, size_t ws_size,
                              hipStream_t stream)
{
    const float* x        = (const float*)d_in[0];
    const float* W        = (const float*)d_in[1];
    const float* lin_bias = (const float*)d_in[2];
    const float* att      = (const float*)d_in[3];
    const float* conv_bias= (const float*)d_in[4];
    const int*   esrc     = (const int*)d_in[5];
    const int*   edst     = (const int*)d_in[6];
    int N = in_sizes[0] / 128;
    int E = in_sizes[5];
    float* out = (float*)d_out;

    char* p = (char*)d_ws;
    float* bbuf   = (float*)p;  p += 256 * 4;
    unsigned short* whi = (unsigned short*)p; p += 16384 * 2;
    unsigned short* wlo = (unsigned short*)p; p += 16384 * 2;
    float* log_x  = (float*)p;  p += (size_t)N * 128 * 4;
    float* s_i    = (float*)p;  p += (size_t)N * 4 * 4;
    float* s_j    = (float*)p;  p += (size_t)N * 4 * 4;
    int*   cnt    = (int*)p;    p += (size_t)N * 4;
    int*   cursor = (int*)p;    p += (size_t)N * 4;
    int*   rowptr = (int*)p;    p += (size_t)(N + 1) * 4;
    int*   csr_src= (int*)p;    p += (size_t)E * 4;
    float* csr_alpha = (float*)p; p += (size_t)E * 4 * 4;

    hipMemsetAsync(cnt, 0, (size_t)N * 2 * 4, stream);

    bias_kernel<<<1, 64, 0, stream>>>(lin_bias, bbuf);
    wsplit_kernel<<<64, 256, 0, stream>>>(W, whi, wlo);
    count_kernel<<<(E + 255) / 256, 256, 0, stream>>>(edst, E, cnt);
    scan_kernel<<<1, 1024, 0, stream>>>(cnt, rowptr, N);
    int nTiles = (N + 15) / 16;
    node_kernel<<<nTiles, 256, 0, stream>>>(x, whi, wlo, bbuf, att, log_x, s_i, s_j, N);
    fill_kernel<<<(E + 255) / 256, 256, 0, stream>>>(esrc, edst, E, s_i, s_j,
                                                     rowptr, cursor, csr_src, csr_alpha);
    aggregate_kernel<<<(N * 64 + 255) / 256, 256, 0, stream>>>(
        rowptr, csr_src, csr_alpha, s_i, s_j, log_x, conv_bias, out, N);
}

// Round 4
// 247.599 us; speedup vs baseline: 3.1418x; 1.2763x over previous
//
#include <hip/hip_runtime.h>
#include <math.h>

#define EPSF 1e-7f
#define MIN_NORM 1e-15f
#define MAXNORM 0.996f   // (1 - 0.004)/sqrt(c), c=1
#define NEG_SLOPE 0.2f

typedef __attribute__((ext_vector_type(8))) short short8;
typedef __attribute__((ext_vector_type(4))) float f32x4;

__device__ __forceinline__ float wave_reduce_sum(float v) {
    #pragma unroll
    for (int m = 1; m < 64; m <<= 1) v += __shfl_xor(v, m, 64);
    return v;
}

__device__ __forceinline__ float artanhf_(float x) {
    x = fminf(fmaxf(x, -1.f + EPSF), 1.f - EPSF);
    return 0.5f * (log1pf(x) - log1pf(-x));
}

__device__ __forceinline__ float lrelu(float a) {
    return a < 0.f ? a * NEG_SLOPE : a;
}

// bf16 round-to-nearest-even (no NaN handling; inputs are tame)
__device__ __forceinline__ unsigned short f2bf(float f) {
    unsigned u = __float_as_uint(f);
    u += 0x7FFFu + ((u >> 16) & 1u);
    return (unsigned short)(u >> 16);
}
__device__ __forceinline__ float bf2f(unsigned short h) {
    return __uint_as_float(((unsigned)h) << 16);
}

// ---- K0: hyp bias = proj(expmap0(lin_bias)), store 128 vals + norm^2 at [128]
__global__ void bias_kernel(const float* __restrict__ lin_bias, float* __restrict__ bbuf) {
    int lane = threadIdx.x;
    float u0 = lin_bias[lane], u1 = lin_bias[lane + 64];
    float n2 = wave_reduce_sum(u0 * u0 + u1 * u1);
    float n = fmaxf(sqrtf(n2), MIN_NORM);
    float s = tanhf(n) / n;
    float b0 = s * u0, b1 = s * u1;
    float bn = fmaxf(tanhf(n), MIN_NORM);   // norm of expmap0 result, analytic
    float fn2 = bn * bn;
    if (bn > MAXNORM) { float f = MAXNORM / bn; b0 *= f; b1 *= f; fn2 = MAXNORM * MAXNORM; }
    bbuf[lane] = b0;
    bbuf[lane + 64] = b1;
    if (lane == 0) bbuf[128] = fn2;
}

// ---- Kw: split W into bf16 hi/lo in B-fragment order.
__global__ void wsplit_kernel(const float* __restrict__ W,
                              unsigned short* __restrict__ whi,
                              unsigned short* __restrict__ wlo) {
    int idx = blockIdx.x * 256 + threadIdx.x;   // 0..16383
    int i = idx & 7, l = (idx >> 3) & 63, ts = idx >> 9;
    int s = ts & 3, t = ts >> 2;
    int o = t * 16 + (l & 15);
    int k = s * 32 + ((l >> 4) * 8) + i;
    float f = W[o * 128 + k];
    unsigned short h = f2bf(f);
    unsigned short lo = f2bf(f - bf2f(h));
    whi[idx] = h;
    wlo[idx] = lo;
}

// ---- K1: per-node transform, MFMA matvec (bf16x3) + hyperbolic chain.
// 256 threads = 4 waves; block handles 16 nodes. log_x stored bf16.
#define DPAD 129
__global__ __launch_bounds__(256) void node_kernel(
    const float* __restrict__ x,
    const unsigned short* __restrict__ whi, const unsigned short* __restrict__ wlo,
    const float* __restrict__ bbuf, const float* __restrict__ att,
    unsigned short* __restrict__ log_xb,
    float* __restrict__ s_i, float* __restrict__ s_j, int N)
{
    __shared__ float mxs[16][DPAD];
    int tid = threadIdx.x, wave = tid >> 6, lane = tid & 63;
    int nbase = blockIdx.x * 16;
    int arow = lane & 15, kgrp = lane >> 4;
    int anode = min(nbase + arow, N - 1);

    f32x4 acc0 = {0.f, 0.f, 0.f, 0.f};
    f32x4 acc1 = {0.f, 0.f, 0.f, 0.f};
    int t0 = wave * 2, t1 = wave * 2 + 1;

    #pragma unroll
    for (int s = 0; s < 4; ++s) {
        const float* xp = x + (size_t)anode * 128 + s * 32 + kgrp * 8;
        float4 xa = *(const float4*)xp;
        float4 xb = *(const float4*)(xp + 4);
        float xv[8] = {xa.x, xa.y, xa.z, xa.w, xb.x, xb.y, xb.z, xb.w};
        short8 ahi, alo;
        #pragma unroll
        for (int i = 0; i < 8; ++i) {
            unsigned short h = f2bf(xv[i]);
            unsigned short l = f2bf(xv[i] - bf2f(h));
            ahi[i] = (short)h;
            alo[i] = (short)l;
        }
        short8 bh0 = *(const short8*)(whi + ((size_t)(t0 * 4 + s) * 64 + lane) * 8);
        short8 bl0 = *(const short8*)(wlo + ((size_t)(t0 * 4 + s) * 64 + lane) * 8);
        short8 bh1 = *(const short8*)(whi + ((size_t)(t1 * 4 + s) * 64 + lane) * 8);
        short8 bl1 = *(const short8*)(wlo + ((size_t)(t1 * 4 + s) * 64 + lane) * 8);
        acc0 = __builtin_amdgcn_mfma_f32_16x16x32_bf16(ahi, bh0, acc0, 0, 0, 0);
        acc0 = __builtin_amdgcn_mfma_f32_16x16x32_bf16(alo, bh0, acc0, 0, 0, 0);
        acc0 = __builtin_amdgcn_mfma_f32_16x16x32_bf16(ahi, bl0, acc0, 0, 0, 0);
        acc1 = __builtin_amdgcn_mfma_f32_16x16x32_bf16(ahi, bh1, acc1, 0, 0, 0);
        acc1 = __builtin_amdgcn_mfma_f32_16x16x32_bf16(alo, bh1, acc1, 0, 0, 0);
        acc1 = __builtin_amdgcn_mfma_f32_16x16x32_bf16(ahi, bl1, acc1, 0, 0, 0);
    }
    #pragma unroll
    for (int r = 0; r < 4; ++r) {
        mxs[kgrp * 4 + r][t0 * 16 + arow] = acc0[r];
        mxs[kgrp * 4 + r][t1 * 16 + arow] = acc1[r];
    }
    __syncthreads();

    float b0 = bbuf[lane], b1 = bbuf[lane + 64];
    float y2 = bbuf[128];
    int hA = lane >> 5, dd = lane & 31;
    float aiA = att[hA * 64 + dd], ajA = att[hA * 64 + 32 + dd];
    float aiB = att[(2 + hA) * 64 + dd], ajB = att[(2 + hA) * 64 + 32 + dd];

    for (int i = 0; i < 4; ++i) {
        int nn = wave * 4 + i;
        int node = nbase + nn;
        if (node >= N) break;
        float x0 = x[(size_t)node * 128 + lane];
        float x1 = x[(size_t)node * 128 + 64 + lane];
        float acc0s = mxs[nn][lane];
        float acc1s = mxs[nn][64 + lane];
        // mobius_matvec
        float xn2 = wave_reduce_sum(x0 * x0 + x1 * x1);
        float mxn2 = wave_reduce_sum(acc0s * acc0s + acc1s * acc1s);
        float xn = fmaxf(sqrtf(xn2), MIN_NORM);
        float mxn = fmaxf(sqrtf(mxn2), MIN_NORM);
        float t = tanhf(mxn / xn * artanhf_(xn));
        float scl = t / mxn;
        float r0 = scl * acc0s, r1 = scl * acc1s;
        if (mxn2 == 0.f) { r0 = 0.f; r1 = 0.f; }
        // proj (norm of r = |t| analytically, but keep reduction-free via t)
        float rn2 = t * t;
        float rn = fmaxf(fabsf(t), MIN_NORM);
        if (mxn2 == 0.f) { rn2 = 0.f; rn = MIN_NORM; }
        float x2 = rn2;
        if (rn > MAXNORM) { float f = MAXNORM / rn; r0 *= f; r1 *= f; x2 = MAXNORM * MAXNORM; }
        // mobius_add(h, bias)
        float xy = wave_reduce_sum(r0 * b0 + r1 * b1);
        float cA = 1.f + 2.f * xy + y2;
        float cB = 1.f - x2;
        float den = fmaxf(1.f + 2.f * xy + x2 * y2, MIN_NORM);
        float h0 = (cA * r0 + cB * b0) / den;
        float h1 = (cA * r1 + cB * b1) / den;
        // proj + logmap0 (post-proj norm analytic)
        float hn2 = wave_reduce_sum(h0 * h0 + h1 * h1);
        float hn = fmaxf(sqrtf(hn2), MIN_NORM);
        float ln2 = hn2;
        if (hn > MAXNORM) { float f = MAXNORM / hn; h0 *= f; h1 *= f; ln2 = MAXNORM * MAXNORM; }
        float lnn = fmaxf(sqrtf(ln2), MIN_NORM);
        float ls = artanhf_(lnn) / lnn;
        float l0 = ls * h0, l1 = ls * h1;
        log_xb[(size_t)node * 128 + lane] = f2bf(l0);
        log_xb[(size_t)node * 128 + 64 + lane] = f2bf(l1);
        // attention partials per 32-lane head group
        float pi = l0 * aiA, pj = l0 * ajA;
        float qi = l1 * aiB, qj = l1 * ajB;
        #pragma unroll
        for (int m = 1; m < 32; m <<= 1) {
            pi += __shfl_xor(pi, m, 64);
            pj += __shfl_xor(pj, m, 64);
            qi += __shfl_xor(qi, m, 64);
            qj += __shfl_xor(qj, m, 64);
        }
        if ((lane & 31) == 0) {
            int g = lane >> 5;
            s_i[(size_t)node * 4 + g] = pi;
            s_j[(size_t)node * 4 + g] = pj;
            s_i[(size_t)node * 4 + 2 + g] = qi;
            s_j[(size_t)node * 4 + 2 + g] = qj;
        }
    }
}

// ---- K2: per-dst in-degree count
__global__ void count_kernel(const int* __restrict__ dst, int E, int* __restrict__ cnt) {
    int e = blockIdx.x * blockDim.x + threadIdx.x;
    if (e < E) atomicAdd(&cnt[dst[e]], 1);
}

// ---- K3a: coalesced per-chunk (256 elems) sums
__global__ void chunksum_kernel(const int* __restrict__ cnt, int* __restrict__ csum, int N) {
    __shared__ int red[4];
    int b = blockIdx.x, t = threadIdx.x;
    int i = b * 256 + t;
    int v = (i < N) ? cnt[i] : 0;
    #pragma unroll
    for (int m = 1; m < 64; m <<= 1) v += __shfl_xor(v, m, 64);
    if ((t & 63) == 0) red[t >> 6] = v;
    __syncthreads();
    if (t == 0) csum[b] = red[0] + red[1] + red[2] + red[3];
}

// ---- K3b: single-block exclusive scan of chunk sums (NCH <= 256); writes rowptr[N]=total
__global__ void chunkscan_kernel(const int* __restrict__ csum, int* __restrict__ coff,
                                 int* __restrict__ rowptr, int NCH, int N) {
    __shared__ int s[256];
    int t = threadIdx.x;
    int v = (t < NCH) ? csum[t] : 0;
    s[t] = v;
    __syncthreads();
    #pragma unroll
    for (int off = 1; off < 256; off <<= 1) {
        int u = (t >= off) ? s[t - off] : 0;
        __syncthreads();
        s[t] += u;
        __syncthreads();
    }
    coff[t] = s[t] - v;   // exclusive offset of chunk t
    if (t == 255) rowptr[N] = s[255];
}

// ---- K3c: emit rowptr (coalesced block-local scan + chunk offset)
__global__ void emit_kernel(const int* __restrict__ cnt, const int* __restrict__ coff,
                            int* __restrict__ rowptr, int N) {
    __shared__ int s[256];
    int b = blockIdx.x, t = threadIdx.x;
    int i = b * 256 + t;
    int v = (i < N) ? cnt[i] : 0;
    s[t] = v;
    __syncthreads();
    #pragma unroll
    for (int off = 1; off < 256; off <<= 1) {
        int u = (t >= off) ? s[t - off] : 0;
        __syncthreads();
        s[t] += u;
        __syncthreads();
    }
    if (i < N) rowptr[i] = coff[b] + s[t] - v;
}

// ---- K4: fill CSR with src ids only
__global__ void fill_kernel(const int* __restrict__ src, const int* __restrict__ dst, int E,
                            const int* __restrict__ rowptr, int* __restrict__ cursor,
                            int* __restrict__ csr_src)
{
    int e = blockIdx.x * blockDim.x + threadIdx.x;
    if (e >= E) return;
    int s_ = src[e], d_ = dst[e];
    int pos = rowptr[d_] + atomicAdd(&cursor[d_], 1);
    csr_src[pos] = s_;
}

// ---- K5: per-node segment softmax + weighted bf16 gather + finalize. One wave/node.
// alpha recomputed on the fly from s_i (own) + s_j (gathered, L2-hot 800 KB).
__global__ __launch_bounds__(256) void aggregate_kernel(
    const int* __restrict__ rowptr, const int* __restrict__ csr_src,
    const float* __restrict__ s_i, const float* __restrict__ s_j,
    const unsigned short* __restrict__ log_xb, const float* __restrict__ conv_bias,
    float* __restrict__ out, int N)
{
    int t = blockIdx.x * blockDim.x + threadIdx.x;
    int n = t >> 6, lane = t & 63;
    if (n >= N) return;
    int base = rowptr[n];
    int deg = rowptr[n + 1] - base;

    float4 si = *(const float4*)(s_i + (size_t)n * 4);
    float4 sjn = *(const float4*)(s_j + (size_t)n * 4);
    float as0 = lrelu(si.x + sjn.x), as1 = lrelu(si.y + sjn.y);
    float as2 = lrelu(si.z + sjn.z), as3 = lrelu(si.w + sjn.w);

    int hm = lane & 3;
    float si_h = hm == 0 ? si.x : (hm == 1 ? si.y : (hm == 2 ? si.z : si.w));
    float a_self_h = hm == 0 ? as0 : (hm == 1 ? as1 : (hm == 2 ? as2 : as3));

    // Phase A: per-head max over {self} ∪ edges, alpha on the fly
    float mx = a_self_h;
    for (int k = lane; k < deg * 4; k += 64) {
        int s_ = csr_src[base + (k >> 2)];
        mx = fmaxf(mx, lrelu(si_h + s_j[(size_t)s_ * 4 + hm]));
    }
    #pragma unroll
    for (int m = 4; m < 64; m <<= 1) mx = fmaxf(mx, __shfl_xor(mx, m, 64));

    // Phase B: per-head denominator
    float dn = (lane < 4) ? __expf(a_self_h - mx) : 0.f;
    for (int k = lane; k < deg * 4; k += 64) {
        int s_ = csr_src[base + (k >> 2)];
        dn += __expf(lrelu(si_h + s_j[(size_t)s_ * 4 + hm]) - mx);
    }
    #pragma unroll
    for (int m = 4; m < 64; m <<= 1) dn += __shfl_xor(dn, m, 64);

    float mx0 = __shfl(mx, 0, 64), mx1 = __shfl(mx, 1, 64);
    float mx2 = __shfl(mx, 2, 64), mx3 = __shfl(mx, 3, 64);
    float dn0 = __shfl(dn, 0, 64), dn1 = __shfl(dn, 1, 64);
    float dn2 = __shfl(dn, 2, 64), dn3 = __shfl(dn, 3, 64);

    int g = lane >> 5;                 // dim lane -> head g; dim lane+64 -> head 2+g
    float mxa = g == 0 ? mx0 : mx1, mxb = g == 0 ? mx2 : mx3;
    float dna = g == 0 ? dn0 : dn1, dnb = g == 0 ? dn2 : dn3;
    float asa = g == 0 ? as0 : as1, asb = g == 0 ? as2 : as3;
    float sia = g == 0 ? si.x : si.y, sib = g == 0 ? si.z : si.w;

    // Phase C: weighted message accumulation (self + edges), bf16 messages
    float acc0 = __expf(asa - mxa) * bf2f(log_xb[(size_t)n * 128 + lane]);
    float acc1 = __expf(asb - mxb) * bf2f(log_xb[(size_t)n * 128 + 64 + lane]);
    int sNext = deg > 0 ? csr_src[base] : 0;
    for (int i = 0; i < deg; ++i) {
        int s_ = sNext;
        if (i + 1 < deg) sNext = csr_src[base + i + 1];
        float a0 = lrelu(sia + s_j[(size_t)s_ * 4 + g]);
        float a1 = lrelu(sib + s_j[(size_t)s_ * 4 + 2 + g]);
        float e0 = __expf(a0 - mxa), e1 = __expf(a1 - mxb);
        acc0 = fmaf(e0, bf2f(log_xb[(size_t)s_ * 128 + lane]), acc0);
        acc1 = fmaf(e1, bf2f(log_xb[(size_t)s_ * 128 + 64 + lane]), acc1);
    }

    // finalize: relu(num/den + bias) -> expmap0 -> proj (post-expmap norm analytic)
    float v0 = acc0 / fmaxf(dna, MIN_NORM) + conv_bias[lane];
    float v1 = acc1 / fmaxf(dnb, MIN_NORM) + conv_bias[lane + 64];
    v0 = fmaxf(v0, 0.f);
    v1 = fmaxf(v1, 0.f);
    float n2 = wave_reduce_sum(v0 * v0 + v1 * v1);
    float nn = fmaxf(sqrtf(n2), MIN_NORM);
    float tv = tanhf(nn);
    float s = tv / nn;
    float r0 = s * v0, r1 = s * v1;
    float rn = fmaxf(tv, MIN_NORM);
    if (rn > MAXNORM) { float f = MAXNORM / rn; r0 *= f; r1 *= f; }
    out[(size_t)n * 128 + lane] = r0;
    out[(size_t)n * 128 + 64 + lane] = r1;
}

extern "C" void kernel_launch(void* const* d_in, const int* in_sizes, int n_in,
                              void* d_out, int out_size, void* d_ws, size_t ws_size,
                              hipStream_t stream)
{
    const float* x        = (const float*)d_in[0];
    const float* W        = (const float*)d_in[1];
    const float* lin_bias = (const float*)d_in[2];
    const float* att      = (const float*)d_in[3];
    const float* conv_bias= (const float*)d_in[4];
    const int*   esrc     = (const int*)d_in[5];
    const int*   edst     = (const int*)d_in[6];
    int N = in_sizes[0] / 128;
    int E = in_sizes[5];
    float* out = (float*)d_out;
    int NCH = (N + 255) / 256;

    char* p = (char*)d_ws;
    float* bbuf   = (float*)p;  p += 256 * 4;
    unsigned short* whi = (unsigned short*)p; p += 16384 * 2;
    unsigned short* wlo = (unsigned short*)p; p += 16384 * 2;
    float* s_i    = (float*)p;  p += (size_t)N * 4 * 4;
    float* s_j    = (float*)p;  p += (size_t)N * 4 * 4;
    int*   cnt    = (int*)p;    p += (size_t)N * 4;
    int*   cursor = (int*)p;    p += (size_t)N * 4;
    int*   rowptr = (int*)p;    p += (size_t)(N + 1) * 4;
    int*   csum   = (int*)p;    p += 256 * 4;
    int*   coff   = (int*)p;    p += 256 * 4;
    int*   csr_src= (int*)p;    p += (size_t)E * 4;
    unsigned short* log_xb = (unsigned short*)p; p += (size_t)N * 128 * 2;

    hipMemsetAsync(cnt, 0, (size_t)N * 2 * 4, stream);

    bias_kernel<<<1, 64, 0, stream>>>(lin_bias, bbuf);
    wsplit_kernel<<<64, 256, 0, stream>>>(W, whi, wlo);
    count_kernel<<<(E + 255) / 256, 256, 0, stream>>>(edst, E, cnt);
    chunksum_kernel<<<NCH, 256, 0, stream>>>(cnt, csum, N);
    chunkscan_kernel<<<1, 256, 0, stream>>>(csum, coff, rowptr, NCH, N);
    emit_kernel<<<NCH, 256, 0, stream>>>(cnt, coff, rowptr, N);
    fill_kernel<<<(E + 255) / 256, 256, 0, stream>>>(esrc, edst, E, rowptr, cursor, csr_src);
    int nTiles = (N + 15) / 16;
    node_kernel<<<nTiles, 256, 0, stream>>>(x, whi, wlo, bbuf, att, log_xb, s_i, s_j, N);
    aggregate_kernel<<<(N * 64 + 255) / 256, 256, 0, stream>>>(
        rowptr, csr_src, s_i, s_j, log_xb, conv_bias, out, N);
}

// Round 5
// 222.381 us; speedup vs baseline: 3.4981x; 1.1134x over previous
//
#include <hip/hip_runtime.h>
#include <math.h>

#define EPSF 1e-7f
#define MIN_NORM 1e-15f
#define MAXNORM 0.996f   // (1 - 0.004)/sqrt(c), c=1
#define NEG_SLOPE 0.2f

typedef __attribute__((ext_vector_type(8))) short short8;
typedef __attribute__((ext_vector_type(4))) float f32x4;

__device__ __forceinline__ float wave_reduce_sum(float v) {
    #pragma unroll
    for (int m = 1; m < 64; m <<= 1) v += __shfl_xor(v, m, 64);
    return v;
}

__device__ __forceinline__ float artanhf_(float x) {
    x = fminf(fmaxf(x, -1.f + EPSF), 1.f - EPSF);
    return 0.5f * (log1pf(x) - log1pf(-x));
}

__device__ __forceinline__ float lrelu(float a) {
    return a < 0.f ? a * NEG_SLOPE : a;
}

// bf16 round-to-nearest-even (no NaN handling; inputs are tame)
__device__ __forceinline__ unsigned short f2bf(float f) {
    unsigned u = __float_as_uint(f);
    u += 0x7FFFu + ((u >> 16) & 1u);
    return (unsigned short)(u >> 16);
}
__device__ __forceinline__ float bf2f(unsigned short h) {
    return __uint_as_float(((unsigned)h) << 16);
}

// ---- K0: prep = wsplit (blocks 0..63) + hyp bias (block 64)
__global__ void prep_kernel(const float* __restrict__ W,
                            unsigned short* __restrict__ whi,
                            unsigned short* __restrict__ wlo,
                            const float* __restrict__ lin_bias,
                            float* __restrict__ bbuf) {
    if (blockIdx.x == 64) {
        if (threadIdx.x >= 64) return;
        int lane = threadIdx.x;
        float u0 = lin_bias[lane], u1 = lin_bias[lane + 64];
        float n2 = wave_reduce_sum(u0 * u0 + u1 * u1);
        float n = fmaxf(sqrtf(n2), MIN_NORM);
        float s = tanhf(n) / n;
        float b0 = s * u0, b1 = s * u1;
        float bn = fmaxf(tanhf(n), MIN_NORM);   // norm of expmap0 result, analytic
        float fn2 = bn * bn;
        if (bn > MAXNORM) { float f = MAXNORM / bn; b0 *= f; b1 *= f; fn2 = MAXNORM * MAXNORM; }
        bbuf[lane] = b0;
        bbuf[lane + 64] = b1;
        if (lane == 0) bbuf[128] = fn2;
        return;
    }
    int idx = blockIdx.x * 256 + threadIdx.x;   // 0..16383
    int i = idx & 7, l = (idx >> 3) & 63, ts = idx >> 9;
    int s = ts & 3, t = ts >> 2;
    int o = t * 16 + (l & 15);
    int k = s * 32 + ((l >> 4) * 8) + i;
    float f = W[o * 128 + k];
    unsigned short h = f2bf(f);
    unsigned short lo = f2bf(f - bf2f(h));
    whi[idx] = h;
    wlo[idx] = lo;
}

// ---- K1: per-node transform, MFMA matvec (bf16x3) + hyperbolic chain.
// 256 threads = 4 waves; block handles 16 nodes. log_x stored bf16.
#define DPAD 129
__global__ __launch_bounds__(256) void node_kernel(
    const float* __restrict__ x,
    const unsigned short* __restrict__ whi, const unsigned short* __restrict__ wlo,
    const float* __restrict__ bbuf, const float* __restrict__ att,
    unsigned short* __restrict__ log_xb,
    float* __restrict__ s_i, float* __restrict__ s_j, int N)
{
    __shared__ float mxs[16][DPAD];
    int tid = threadIdx.x, wave = tid >> 6, lane = tid & 63;
    int nbase = blockIdx.x * 16;
    int arow = lane & 15, kgrp = lane >> 4;
    int anode = min(nbase + arow, N - 1);

    f32x4 acc0 = {0.f, 0.f, 0.f, 0.f};
    f32x4 acc1 = {0.f, 0.f, 0.f, 0.f};
    int t0 = wave * 2, t1 = wave * 2 + 1;

    #pragma unroll
    for (int s = 0; s < 4; ++s) {
        const float* xp = x + (size_t)anode * 128 + s * 32 + kgrp * 8;
        float4 xa = *(const float4*)xp;
        float4 xb = *(const float4*)(xp + 4);
        float xv[8] = {xa.x, xa.y, xa.z, xa.w, xb.x, xb.y, xb.z, xb.w};
        short8 ahi, alo;
        #pragma unroll
        for (int i = 0; i < 8; ++i) {
            unsigned short h = f2bf(xv[i]);
            unsigned short l = f2bf(xv[i] - bf2f(h));
            ahi[i] = (short)h;
            alo[i] = (short)l;
        }
        short8 bh0 = *(const short8*)(whi + ((size_t)(t0 * 4 + s) * 64 + lane) * 8);
        short8 bl0 = *(const short8*)(wlo + ((size_t)(t0 * 4 + s) * 64 + lane) * 8);
        short8 bh1 = *(const short8*)(whi + ((size_t)(t1 * 4 + s) * 64 + lane) * 8);
        short8 bl1 = *(const short8*)(wlo + ((size_t)(t1 * 4 + s) * 64 + lane) * 8);
        acc0 = __builtin_amdgcn_mfma_f32_16x16x32_bf16(ahi, bh0, acc0, 0, 0, 0);
        acc0 = __builtin_amdgcn_mfma_f32_16x16x32_bf16(alo, bh0, acc0, 0, 0, 0);
        acc0 = __builtin_amdgcn_mfma_f32_16x16x32_bf16(ahi, bl0, acc0, 0, 0, 0);
        acc1 = __builtin_amdgcn_mfma_f32_16x16x32_bf16(ahi, bh1, acc1, 0, 0, 0);
        acc1 = __builtin_amdgcn_mfma_f32_16x16x32_bf16(alo, bh1, acc1, 0, 0, 0);
        acc1 = __builtin_amdgcn_mfma_f32_16x16x32_bf16(ahi, bl1, acc1, 0, 0, 0);
    }
    #pragma unroll
    for (int r = 0; r < 4; ++r) {
        mxs[kgrp * 4 + r][t0 * 16 + arow] = acc0[r];
        mxs[kgrp * 4 + r][t1 * 16 + arow] = acc1[r];
    }
    __syncthreads();

    float b0 = bbuf[lane], b1 = bbuf[lane + 64];
    float y2 = bbuf[128];
    int hA = lane >> 5, dd = lane & 31;
    float aiA = att[hA * 64 + dd], ajA = att[hA * 64 + 32 + dd];
    float aiB = att[(2 + hA) * 64 + dd], ajB = att[(2 + hA) * 64 + 32 + dd];

    for (int i = 0; i < 4; ++i) {
        int nn = wave * 4 + i;
        int node = nbase + nn;
        if (node >= N) break;
        float x0 = x[(size_t)node * 128 + lane];
        float x1 = x[(size_t)node * 128 + 64 + lane];
        float acc0s = mxs[nn][lane];
        float acc1s = mxs[nn][64 + lane];
        // mobius_matvec
        float xn2 = wave_reduce_sum(x0 * x0 + x1 * x1);
        float mxn2 = wave_reduce_sum(acc0s * acc0s + acc1s * acc1s);
        float xn = fmaxf(sqrtf(xn2), MIN_NORM);
        float mxn = fmaxf(sqrtf(mxn2), MIN_NORM);
        float t = tanhf(mxn / xn * artanhf_(xn));
        float scl = t / mxn;
        float r0 = scl * acc0s, r1 = scl * acc1s;
        if (mxn2 == 0.f) { r0 = 0.f; r1 = 0.f; }
        // proj (norm of r = |t| analytically)
        float rn2 = t * t;
        float rn = fmaxf(fabsf(t), MIN_NORM);
        if (mxn2 == 0.f) { rn2 = 0.f; rn = MIN_NORM; }
        float x2 = rn2;
        if (rn > MAXNORM) { float f = MAXNORM / rn; r0 *= f; r1 *= f; x2 = MAXNORM * MAXNORM; }
        // mobius_add(h, bias)
        float xy = wave_reduce_sum(r0 * b0 + r1 * b1);
        float cA = 1.f + 2.f * xy + y2;
        float cB = 1.f - x2;
        float den = fmaxf(1.f + 2.f * xy + x2 * y2, MIN_NORM);
        float h0 = (cA * r0 + cB * b0) / den;
        float h1 = (cA * r1 + cB * b1) / den;
        // proj + logmap0 (post-proj norm analytic)
        float hn2 = wave_reduce_sum(h0 * h0 + h1 * h1);
        float hn = fmaxf(sqrtf(hn2), MIN_NORM);
        float ln2 = hn2;
        if (hn > MAXNORM) { float f = MAXNORM / hn; h0 *= f; h1 *= f; ln2 = MAXNORM * MAXNORM; }
        float lnn = fmaxf(sqrtf(ln2), MIN_NORM);
        float ls = artanhf_(lnn) / lnn;
        float l0 = ls * h0, l1 = ls * h1;
        log_xb[(size_t)node * 128 + lane] = f2bf(l0);
        log_xb[(size_t)node * 128 + 64 + lane] = f2bf(l1);
        // attention partials per 32-lane head group
        float pi = l0 * aiA, pj = l0 * ajA;
        float qi = l1 * aiB, qj = l1 * ajB;
        #pragma unroll
        for (int m = 1; m < 32; m <<= 1) {
            pi += __shfl_xor(pi, m, 64);
            pj += __shfl_xor(pj, m, 64);
            qi += __shfl_xor(qi, m, 64);
            qj += __shfl_xor(qj, m, 64);
        }
        if ((lane & 31) == 0) {
            int g = lane >> 5;
            s_i[(size_t)node * 4 + g] = pi;
            s_j[(size_t)node * 4 + g] = pj;
            s_i[(size_t)node * 4 + 2 + g] = qi;
            s_j[(size_t)node * 4 + 2 + g] = qj;
        }
    }
}

// ---- K2: per-dst in-degree count
__global__ void count_kernel(const int* __restrict__ dst, int E, int* __restrict__ cnt) {
    int e = blockIdx.x * blockDim.x + threadIdx.x;
    if (e < E) atomicAdd(&cnt[dst[e]], 1);
}

// ---- K3a: coalesced per-chunk (256 elems) sums
__global__ void chunksum_kernel(const int* __restrict__ cnt, int* __restrict__ csum, int N) {
    __shared__ int red[4];
    int b = blockIdx.x, t = threadIdx.x;
    int i = b * 256 + t;
    int v = (i < N) ? cnt[i] : 0;
    #pragma unroll
    for (int m = 1; m < 64; m <<= 1) v += __shfl_xor(v, m, 64);
    if ((t & 63) == 0) red[t >> 6] = v;
    __syncthreads();
    if (t == 0) csum[b] = red[0] + red[1] + red[2] + red[3];
}

// ---- K3b: single-block exclusive scan of chunk sums (NCH <= 256)
__global__ void chunkscan_kernel(const int* __restrict__ csum, int* __restrict__ coff,
                                 int* __restrict__ rowptr, int NCH, int N) {
    __shared__ int s[256];
    int t = threadIdx.x;
    int v = (t < NCH) ? csum[t] : 0;
    s[t] = v;
    __syncthreads();
    #pragma unroll
    for (int off = 1; off < 256; off <<= 1) {
        int u = (t >= off) ? s[t - off] : 0;
        __syncthreads();
        s[t] += u;
        __syncthreads();
    }
    coff[t] = s[t] - v;   // exclusive offset of chunk t
    if (t == 255) rowptr[N] = s[255];
}

// ---- K3c: emit rowptr AND cursor (= rowptr copy for fill's single-atomic scheme)
__global__ void emit_kernel(const int* __restrict__ cnt, const int* __restrict__ coff,
                            int* __restrict__ rowptr, int* __restrict__ cursor, int N) {
    __shared__ int s[256];
    int b = blockIdx.x, t = threadIdx.x;
    int i = b * 256 + t;
    int v = (i < N) ? cnt[i] : 0;
    s[t] = v;
    __syncthreads();
    #pragma unroll
    for (int off = 1; off < 256; off <<= 1) {
        int u = (t >= off) ? s[t - off] : 0;
        __syncthreads();
        s[t] += u;
        __syncthreads();
    }
    if (i < N) {
        int r = coff[b] + s[t] - v;
        rowptr[i] = r;
        cursor[i] = r;
    }
}

// ---- K4: fill CSR src ids — one atomic per edge, absolute position
__global__ void fill_kernel(const int* __restrict__ src, const int* __restrict__ dst, int E,
                            int* __restrict__ cursor, int* __restrict__ csr_src)
{
    int e = blockIdx.x * blockDim.x + threadIdx.x;
    if (e >= E) return;
    int s_ = src[e], d_ = dst[e];
    int pos = atomicAdd(&cursor[d_], 1);
    csr_src[pos] = s_;
}

// ---- K5: single-pass online softmax-aggregate + finalize. One wave/node.
// No max subtraction (scores are O(0.05): exp-safe, softmax shift-invariant).
// e is uniform across each 32-lane head group -> dn needs no reduction.
__global__ __launch_bounds__(256) void aggregate_kernel(
    const int* __restrict__ rowptr, const int* __restrict__ csr_src,
    const float* __restrict__ s_i, const float* __restrict__ s_j,
    const unsigned short* __restrict__ log_xb, const float* __restrict__ conv_bias,
    float* __restrict__ out, int N)
{
    int t = blockIdx.x * blockDim.x + threadIdx.x;
    int n = t >> 6, lane = t & 63;
    if (n >= N) return;
    int base = rowptr[n];
    int deg = rowptr[n + 1] - base;
    int g = lane >> 5;                 // dim lane -> head g; dim lane+64 -> head 2+g

    float4 si = *(const float4*)(s_i + (size_t)n * 4);
    float4 sjn = *(const float4*)(s_j + (size_t)n * 4);
    float sia = g == 0 ? si.x : si.y, sib = g == 0 ? si.z : si.w;
    float sjna = g == 0 ? sjn.x : sjn.y, sjnb = g == 0 ? sjn.z : sjn.w;

    // self-loop
    float ea = __expf(lrelu(sia + sjna));
    float eb = __expf(lrelu(sib + sjnb));
    float dna = ea, dnb = eb;
    float acc0 = ea * bf2f(log_xb[(size_t)n * 128 + lane]);
    float acc1 = eb * bf2f(log_xb[(size_t)n * 128 + 64 + lane]);

    const int* cs = csr_src + base;
    int i = 0;
    for (; i + 4 <= deg; i += 4) {
        int s0 = cs[i], s1 = cs[i + 1], s2 = cs[i + 2], s3 = cs[i + 3];
        float a0a = s_j[(size_t)s0 * 4 + g],     a0b = s_j[(size_t)s0 * 4 + 2 + g];
        float a1a = s_j[(size_t)s1 * 4 + g],     a1b = s_j[(size_t)s1 * 4 + 2 + g];
        float a2a = s_j[(size_t)s2 * 4 + g],     a2b = s_j[(size_t)s2 * 4 + 2 + g];
        float a3a = s_j[(size_t)s3 * 4 + g],     a3b = s_j[(size_t)s3 * 4 + 2 + g];
        unsigned short m0a = log_xb[(size_t)s0 * 128 + lane], m0b = log_xb[(size_t)s0 * 128 + 64 + lane];
        unsigned short m1a = log_xb[(size_t)s1 * 128 + lane], m1b = log_xb[(size_t)s1 * 128 + 64 + lane];
        unsigned short m2a = log_xb[(size_t)s2 * 128 + lane], m2b = log_xb[(size_t)s2 * 128 + 64 + lane];
        unsigned short m3a = log_xb[(size_t)s3 * 128 + lane], m3b = log_xb[(size_t)s3 * 128 + 64 + lane];
        float e0a = __expf(lrelu(sia + a0a)), e0b = __expf(lrelu(sib + a0b));
        float e1a = __expf(lrelu(sia + a1a)), e1b = __expf(lrelu(sib + a1b));
        float e2a = __expf(lrelu(sia + a2a)), e2b = __expf(lrelu(sib + a2b));
        float e3a = __expf(lrelu(sia + a3a)), e3b = __expf(lrelu(sib + a3b));
        dna += e0a + e1a + e2a + e3a;
        dnb += e0b + e1b + e2b + e3b;
        acc0 = fmaf(e0a, bf2f(m0a), acc0);
        acc1 = fmaf(e0b, bf2f(m0b), acc1);
        acc0 = fmaf(e1a, bf2f(m1a), acc0);
        acc1 = fmaf(e1b, bf2f(m1b), acc1);
        acc0 = fmaf(e2a, bf2f(m2a), acc0);
        acc1 = fmaf(e2b, bf2f(m2b), acc1);
        acc0 = fmaf(e3a, bf2f(m3a), acc0);
        acc1 = fmaf(e3b, bf2f(m3b), acc1);
    }
    for (; i < deg; ++i) {
        int s_ = cs[i];
        float aa = s_j[(size_t)s_ * 4 + g], ab = s_j[(size_t)s_ * 4 + 2 + g];
        unsigned short ma = log_xb[(size_t)s_ * 128 + lane];
        unsigned short mb = log_xb[(size_t)s_ * 128 + 64 + lane];
        float eA = __expf(lrelu(sia + aa)), eB = __expf(lrelu(sib + ab));
        dna += eA; dnb += eB;
        acc0 = fmaf(eA, bf2f(ma), acc0);
        acc1 = fmaf(eB, bf2f(mb), acc1);
    }

    // finalize: relu(num/den + bias) -> expmap0 -> proj (post-expmap norm analytic)
    float v0 = acc0 / fmaxf(dna, MIN_NORM) + conv_bias[lane];
    float v1 = acc1 / fmaxf(dnb, MIN_NORM) + conv_bias[lane + 64];
    v0 = fmaxf(v0, 0.f);
    v1 = fmaxf(v1, 0.f);
    float n2 = wave_reduce_sum(v0 * v0 + v1 * v1);
    float nn = fmaxf(sqrtf(n2), MIN_NORM);
    float tv = tanhf(nn);
    float s = tv / nn;
    float r0 = s * v0, r1 = s * v1;
    float rn = fmaxf(tv, MIN_NORM);
    if (rn > MAXNORM) { float f = MAXNORM / rn; r0 *= f; r1 *= f; }
    out[(size_t)n * 128 + lane] = r0;
    out[(size_t)n * 128 + 64 + lane] = r1;
}

extern "C" void kernel_launch(void* const* d_in, const int* in_sizes, int n_in,
                              void* d_out, int out_size, void* d_ws, size_t ws_size,
                              hipStream_t stream)
{
    const float* x        = (const float*)d_in[0];
    const float* W        = (const float*)d_in[1];
    const float* lin_bias = (const float*)d_in[2];
    const float* att      = (const float*)d_in[3];
    const float* conv_bias= (const float*)d_in[4];
    const int*   esrc     = (const int*)d_in[5];
    const int*   edst     = (const int*)d_in[6];
    int N = in_sizes[0] / 128;
    int E = in_sizes[5];
    float* out = (float*)d_out;
    int NCH = (N + 255) / 256;

    char* p = (char*)d_ws;
    float* bbuf   = (float*)p;  p += 256 * 4;
    unsigned short* whi = (unsigned short*)p; p += 16384 * 2;
    unsigned short* wlo = (unsigned short*)p; p += 16384 * 2;
    float* s_i    = (float*)p;  p += (size_t)N * 4 * 4;
    float* s_j    = (float*)p;  p += (size_t)N * 4 * 4;
    int*   cnt    = (int*)p;    p += (size_t)N * 4;
    int*   cursor = (int*)p;    p += (size_t)N * 4;
    int*   rowptr = (int*)p;    p += (size_t)(N + 1) * 4;
    int*   csum   = (int*)p;    p += 256 * 4;
    int*   coff   = (int*)p;    p += 256 * 4;
    int*   csr_src= (int*)p;    p += (size_t)E * 4;
    unsigned short* log_xb = (unsigned short*)p; p += (size_t)N * 128 * 2;

    hipMemsetAsync(cnt, 0, (size_t)N * 4, stream);

    prep_kernel<<<65, 256, 0, stream>>>(W, whi, wlo, lin_bias, bbuf);
    count_kernel<<<(E + 255) / 256, 256, 0, stream>>>(edst, E, cnt);
    chunksum_kernel<<<NCH, 256, 0, stream>>>(cnt, csum, N);
    chunkscan_kernel<<<1, 256, 0, stream>>>(csum, coff, rowptr, NCH, N);
    emit_kernel<<<NCH, 256, 0, stream>>>(cnt, coff, rowptr, cursor, N);
    fill_kernel<<<(E + 255) / 256, 256, 0, stream>>>(esrc, edst, E, cursor, csr_src);
    int nTiles = (N + 15) / 16;
    node_kernel<<<nTiles, 256, 0, stream>>>(x, whi, wlo, bbuf, att, log_xb, s_i, s_j, N);
    aggregate_kernel<<<(N * 64 + 255) / 256, 256, 0, stream>>>(
        rowptr, csr_src, s_i, s_j, log_xb, conv_bias, out, N);
}

// Round 6
// 193.507 us; speedup vs baseline: 4.0200x; 1.1492x over previous
//
#include <hip/hip_runtime.h>
#include <math.h>

#define EPSF 1e-7f
#define MIN_NORM 1e-15f
#define MAXNORM 0.996f   // (1 - 0.004)/sqrt(c), c=1
#define NEG_SLOPE 0.2f

typedef __attribute__((ext_vector_type(8))) short short8;
typedef __attribute__((ext_vector_type(4))) float f32x4;

__device__ __forceinline__ float wave_reduce_sum(float v) {
    #pragma unroll
    for (int m = 1; m < 64; m <<= 1) v += __shfl_xor(v, m, 64);
    return v;
}

__device__ __forceinline__ float artanhf_(float x) {
    x = fminf(fmaxf(x, -1.f + EPSF), 1.f - EPSF);
    return 0.5f * (log1pf(x) - log1pf(-x));
}

__device__ __forceinline__ float lrelu(float a) {
    return a < 0.f ? a * NEG_SLOPE : a;
}

// bf16 round-to-nearest-even (no NaN handling; inputs are tame)
__device__ __forceinline__ unsigned short f2bf(float f) {
    unsigned u = __float_as_uint(f);
    u += 0x7FFFu + ((u >> 16) & 1u);
    return (unsigned short)(u >> 16);
}
__device__ __forceinline__ float bf2f(unsigned short h) {
    return __uint_as_float(((unsigned)h) << 16);
}

// ---- K0: prep = wsplit (blocks 0..63) + hyp bias (block 64)
__global__ void prep_kernel(const float* __restrict__ W,
                            unsigned short* __restrict__ whi,
                            unsigned short* __restrict__ wlo,
                            const float* __restrict__ lin_bias,
                            float* __restrict__ bbuf) {
    if (blockIdx.x == 64) {
        if (threadIdx.x >= 64) return;
        int lane = threadIdx.x;
        float u0 = lin_bias[lane], u1 = lin_bias[lane + 64];
        float n2 = wave_reduce_sum(u0 * u0 + u1 * u1);
        float n = fmaxf(sqrtf(n2), MIN_NORM);
        float s = tanhf(n) / n;
        float b0 = s * u0, b1 = s * u1;
        float bn = fmaxf(tanhf(n), MIN_NORM);   // norm of expmap0 result, analytic
        float fn2 = bn * bn;
        if (bn > MAXNORM) { float f = MAXNORM / bn; b0 *= f; b1 *= f; fn2 = MAXNORM * MAXNORM; }
        bbuf[lane] = b0;
        bbuf[lane + 64] = b1;
        if (lane == 0) bbuf[128] = fn2;
        return;
    }
    int idx = blockIdx.x * 256 + threadIdx.x;   // 0..16383
    int i = idx & 7, l = (idx >> 3) & 63, ts = idx >> 9;
    int s = ts & 3, t = ts >> 2;
    int o = t * 16 + (l & 15);
    int k = s * 32 + ((l >> 4) * 8) + i;
    float f = W[o * 128 + k];
    unsigned short h = f2bf(f);
    unsigned short lo = f2bf(f - bf2f(h));
    whi[idx] = h;
    wlo[idx] = lo;
}

// ---- K1: per-node transform, MFMA matvec (bf16x3) + 16-lane-per-node chain.
// 256 threads = 4 waves; block handles 16 nodes.
#define DPAD 132   // 16B-aligned rows for float4 LDS reads
__global__ __launch_bounds__(256) void node_kernel(
    const float* __restrict__ x,
    const unsigned short* __restrict__ whi, const unsigned short* __restrict__ wlo,
    const float* __restrict__ bbuf, const float* __restrict__ att,
    unsigned short* __restrict__ log_xb,
    float* __restrict__ s_i, float* __restrict__ s_j, int N)
{
    __shared__ float mxs[16][DPAD];
    __shared__ float xn2s[16];
    int tid = threadIdx.x, wave = tid >> 6, lane = tid & 63;
    int nbase = blockIdx.x * 16;
    int arow = lane & 15, kgrp = lane >> 4;
    int anode = min(nbase + arow, N - 1);

    f32x4 acc0 = {0.f, 0.f, 0.f, 0.f};
    f32x4 acc1 = {0.f, 0.f, 0.f, 0.f};
    int t0 = wave * 2, t1 = wave * 2 + 1;
    float x2loc = 0.f;

    #pragma unroll
    for (int s = 0; s < 4; ++s) {
        const float* xp = x + (size_t)anode * 128 + s * 32 + kgrp * 8;
        float4 xa = *(const float4*)xp;
        float4 xb = *(const float4*)(xp + 4);
        float xv[8] = {xa.x, xa.y, xa.z, xa.w, xb.x, xb.y, xb.z, xb.w};
        short8 ahi, alo;
        #pragma unroll
        for (int i = 0; i < 8; ++i) {
            unsigned short h = f2bf(xv[i]);
            unsigned short l = f2bf(xv[i] - bf2f(h));
            ahi[i] = (short)h;
            alo[i] = (short)l;
        }
        if (wave == 0) {
            #pragma unroll
            for (int i = 0; i < 8; ++i) x2loc = fmaf(xv[i], xv[i], x2loc);
        }
        short8 bh0 = *(const short8*)(whi + ((size_t)(t0 * 4 + s) * 64 + lane) * 8);
        short8 bl0 = *(const short8*)(wlo + ((size_t)(t0 * 4 + s) * 64 + lane) * 8);
        short8 bh1 = *(const short8*)(whi + ((size_t)(t1 * 4 + s) * 64 + lane) * 8);
        short8 bl1 = *(const short8*)(wlo + ((size_t)(t1 * 4 + s) * 64 + lane) * 8);
        acc0 = __builtin_amdgcn_mfma_f32_16x16x32_bf16(ahi, bh0, acc0, 0, 0, 0);
        acc0 = __builtin_amdgcn_mfma_f32_16x16x32_bf16(alo, bh0, acc0, 0, 0, 0);
        acc0 = __builtin_amdgcn_mfma_f32_16x16x32_bf16(ahi, bl0, acc0, 0, 0, 0);
        acc1 = __builtin_amdgcn_mfma_f32_16x16x32_bf16(ahi, bh1, acc1, 0, 0, 0);
        acc1 = __builtin_amdgcn_mfma_f32_16x16x32_bf16(alo, bh1, acc1, 0, 0, 0);
        acc1 = __builtin_amdgcn_mfma_f32_16x16x32_bf16(ahi, bl1, acc1, 0, 0, 0);
    }
    if (wave == 0) {
        x2loc += __shfl_xor(x2loc, 16, 64);
        x2loc += __shfl_xor(x2loc, 32, 64);
        if (lane < 16) xn2s[lane] = x2loc;
    }
    #pragma unroll
    for (int r = 0; r < 4; ++r) {
        mxs[kgrp * 4 + r][t0 * 16 + arow] = acc0[r];
        mxs[kgrp * 4 + r][t1 * 16 + arow] = acc1[r];
    }
    __syncthreads();

    // ---- chain: 16 lanes per node, 8 dims per lane, 4 nodes per wave ----
    int g16 = lane >> 4, l16 = lane & 15;
    int nn = wave * 4 + g16;
    int node = nbase + nn;
    if (node < N) {
        int head = l16 >> 2;
        int dbase = l16 * 8;
        int dd8 = (l16 & 3) * 8;
        float bb[8], aiv[8], ajv[8];
        #pragma unroll
        for (int j = 0; j < 8; ++j) {
            bb[j] = bbuf[dbase + j];
            aiv[j] = att[head * 64 + dd8 + j];
            ajv[j] = att[head * 64 + 32 + dd8 + j];
        }
        float y2 = bbuf[128];

        float4 va = *(const float4*)&mxs[nn][dbase];
        float4 vb = *(const float4*)&mxs[nn][dbase + 4];
        float v[8] = {va.x, va.y, va.z, va.w, vb.x, vb.y, vb.z, vb.w};

        float mq = 0.f;
        #pragma unroll
        for (int j = 0; j < 8; ++j) mq = fmaf(v[j], v[j], mq);
        #pragma unroll
        for (int m = 1; m < 16; m <<= 1) mq += __shfl_xor(mq, m, 64);

        float xn2 = xn2s[nn];
        float xn = fmaxf(sqrtf(xn2), MIN_NORM);
        float mxn = fmaxf(sqrtf(mq), MIN_NORM);
        float t = tanhf(mxn / xn * artanhf_(xn));
        float scl = t / mxn;
        bool zero = (mq == 0.f);
        float r[8];
        #pragma unroll
        for (int j = 0; j < 8; ++j) r[j] = zero ? 0.f : scl * v[j];
        // proj: ||r|| = |t| analytically
        float rn2 = zero ? 0.f : t * t;
        float rn = zero ? MIN_NORM : fmaxf(fabsf(t), MIN_NORM);
        float x2 = rn2;
        if (rn > MAXNORM) {
            float f = MAXNORM / rn;
            #pragma unroll
            for (int j = 0; j < 8; ++j) r[j] *= f;
            x2 = MAXNORM * MAXNORM;
        }
        // mobius_add(r, bias)
        float xy = 0.f;
        #pragma unroll
        for (int j = 0; j < 8; ++j) xy = fmaf(r[j], bb[j], xy);
        #pragma unroll
        for (int m = 1; m < 16; m <<= 1) xy += __shfl_xor(xy, m, 64);
        float cA = 1.f + 2.f * xy + y2;
        float cB = 1.f - x2;
        float dn = fmaxf(1.f + 2.f * xy + x2 * y2, MIN_NORM);
        float inv = 1.f / dn;
        float h[8];
        #pragma unroll
        for (int j = 0; j < 8; ++j) h[j] = (cA * r[j] + cB * bb[j]) * inv;
        // proj + logmap0
        float hq = 0.f;
        #pragma unroll
        for (int j = 0; j < 8; ++j) hq = fmaf(h[j], h[j], hq);
        #pragma unroll
        for (int m = 1; m < 16; m <<= 1) hq += __shfl_xor(hq, m, 64);
        float hn = fmaxf(sqrtf(hq), MIN_NORM);
        float ln2 = hq;
        if (hn > MAXNORM) {
            float f = MAXNORM / hn;
            #pragma unroll
            for (int j = 0; j < 8; ++j) h[j] *= f;
            ln2 = MAXNORM * MAXNORM;
        }
        float lnn = fmaxf(sqrtf(ln2), MIN_NORM);
        float ls = artanhf_(lnn) / lnn;
        float lv[8];
        #pragma unroll
        for (int j = 0; j < 8; ++j) lv[j] = ls * h[j];
        // store bf16 (16 B per lane, coalesced)
        uint4 pk;
        pk.x = (unsigned)f2bf(lv[0]) | ((unsigned)f2bf(lv[1]) << 16);
        pk.y = (unsigned)f2bf(lv[2]) | ((unsigned)f2bf(lv[3]) << 16);
        pk.z = (unsigned)f2bf(lv[4]) | ((unsigned)f2bf(lv[5]) << 16);
        pk.w = (unsigned)f2bf(lv[6]) | ((unsigned)f2bf(lv[7]) << 16);
        *(uint4*)&log_xb[(size_t)node * 128 + dbase] = pk;
        // attention partials: reduce over the 4 lanes of this head
        float pi = 0.f, pj = 0.f;
        #pragma unroll
        for (int j = 0; j < 8; ++j) {
            pi = fmaf(lv[j], aiv[j], pi);
            pj = fmaf(lv[j], ajv[j], pj);
        }
        pi += __shfl_xor(pi, 1, 64); pi += __shfl_xor(pi, 2, 64);
        pj += __shfl_xor(pj, 1, 64); pj += __shfl_xor(pj, 2, 64);
        if ((l16 & 3) == 0) {
            s_i[(size_t)node * 4 + head] = pi;
            s_j[(size_t)node * 4 + head] = pj;
        }
    }
}

// ---- K2: per-dst in-degree count
__global__ void count_kernel(const int* __restrict__ dst, int E, int* __restrict__ cnt) {
    int e = blockIdx.x * blockDim.x + threadIdx.x;
    if (e < E) atomicAdd(&cnt[dst[e]], 1);
}

// ---- K3a: coalesced per-chunk (256 elems) sums
__global__ void chunksum_kernel(const int* __restrict__ cnt, int* __restrict__ csum, int N) {
    __shared__ int red[4];
    int b = blockIdx.x, t = threadIdx.x;
    int i = b * 256 + t;
    int v = (i < N) ? cnt[i] : 0;
    #pragma unroll
    for (int m = 1; m < 64; m <<= 1) v += __shfl_xor(v, m, 64);
    if ((t & 63) == 0) red[t >> 6] = v;
    __syncthreads();
    if (t == 0) csum[b] = red[0] + red[1] + red[2] + red[3];
}

// ---- K3b: single-block exclusive scan of chunk sums (NCH <= 256)
__global__ void chunkscan_kernel(const int* __restrict__ csum, int* __restrict__ coff,
                                 int* __restrict__ rowptr, int NCH, int N) {
    __shared__ int s[256];
    int t = threadIdx.x;
    int v = (t < NCH) ? csum[t] : 0;
    s[t] = v;
    __syncthreads();
    #pragma unroll
    for (int off = 1; off < 256; off <<= 1) {
        int u = (t >= off) ? s[t - off] : 0;
        __syncthreads();
        s[t] += u;
        __syncthreads();
    }
    coff[t] = s[t] - v;   // exclusive offset of chunk t
    if (t == 255) rowptr[N] = s[255];
}

// ---- K3c: emit rowptr AND cursor (= rowptr copy for fill's single-atomic scheme)
__global__ void emit_kernel(const int* __restrict__ cnt, const int* __restrict__ coff,
                            int* __restrict__ rowptr, int* __restrict__ cursor, int N) {
    __shared__ int s[256];
    int b = blockIdx.x, t = threadIdx.x;
    int i = b * 256 + t;
    int v = (i < N) ? cnt[i] : 0;
    s[t] = v;
    __syncthreads();
    #pragma unroll
    for (int off = 1; off < 256; off <<= 1) {
        int u = (t >= off) ? s[t - off] : 0;
        __syncthreads();
        s[t] += u;
        __syncthreads();
    }
    if (i < N) {
        int r = coff[b] + s[t] - v;
        rowptr[i] = r;
        cursor[i] = r;
    }
}

// ---- K4: fill CSR src ids — one atomic per edge, absolute position
__global__ void fill_kernel(const int* __restrict__ src, const int* __restrict__ dst, int E,
                            int* __restrict__ cursor, int* __restrict__ csr_src)
{
    int e = blockIdx.x * blockDim.x + threadIdx.x;
    if (e >= E) return;
    int s_ = src[e], d_ = dst[e];
    int pos = atomicAdd(&cursor[d_], 1);
    csr_src[pos] = s_;
}

// ---- K5: single-pass online softmax-aggregate + finalize. One wave/node.
__global__ __launch_bounds__(256) void aggregate_kernel(
    const int* __restrict__ rowptr, const int* __restrict__ csr_src,
    const float* __restrict__ s_i, const float* __restrict__ s_j,
    const unsigned short* __restrict__ log_xb, const float* __restrict__ conv_bias,
    float* __restrict__ out, int N)
{
    int t = blockIdx.x * blockDim.x + threadIdx.x;
    int n = t >> 6, lane = t & 63;
    if (n >= N) return;
    int base = rowptr[n];
    int deg = rowptr[n + 1] - base;
    int g = lane >> 5;                 // dim lane -> head g; dim lane+64 -> head 2+g

    float4 si = *(const float4*)(s_i + (size_t)n * 4);
    float4 sjn = *(const float4*)(s_j + (size_t)n * 4);
    float sia = g == 0 ? si.x : si.y, sib = g == 0 ? si.z : si.w;
    float sjna = g == 0 ? sjn.x : sjn.y, sjnb = g == 0 ? sjn.z : sjn.w;

    // self-loop
    float ea = __expf(lrelu(sia + sjna));
    float eb = __expf(lrelu(sib + sjnb));
    float dna = ea, dnb = eb;
    float acc0 = ea * bf2f(log_xb[(size_t)n * 128 + lane]);
    float acc1 = eb * bf2f(log_xb[(size_t)n * 128 + 64 + lane]);

    const int* cs = csr_src + base;
    int i = 0;
    for (; i + 4 <= deg; i += 4) {
        int s0 = cs[i], s1 = cs[i + 1], s2 = cs[i + 2], s3 = cs[i + 3];
        float a0a = s_j[(size_t)s0 * 4 + g],     a0b = s_j[(size_t)s0 * 4 + 2 + g];
        float a1a = s_j[(size_t)s1 * 4 + g],     a1b = s_j[(size_t)s1 * 4 + 2 + g];
        float a2a = s_j[(size_t)s2 * 4 + g],     a2b = s_j[(size_t)s2 * 4 + 2 + g];
        float a3a = s_j[(size_t)s3 * 4 + g],     a3b = s_j[(size_t)s3 * 4 + 2 + g];
        unsigned short m0a = log_xb[(size_t)s0 * 128 + lane], m0b = log_xb[(size_t)s0 * 128 + 64 + lane];
        unsigned short m1a = log_xb[(size_t)s1 * 128 + lane], m1b = log_xb[(size_t)s1 * 128 + 64 + lane];
        unsigned short m2a = log_xb[(size_t)s2 * 128 + lane], m2b = log_xb[(size_t)s2 * 128 + 64 + lane];
        unsigned short m3a = log_xb[(size_t)s3 * 128 + lane], m3b = log_xb[(size_t)s3 * 128 + 64 + lane];
        float e0a = __expf(lrelu(sia + a0a)), e0b = __expf(lrelu(sib + a0b));
        float e1a = __expf(lrelu(sia + a1a)), e1b = __expf(lrelu(sib + a1b));
        float e2a = __expf(lrelu(sia + a2a)), e2b = __expf(lrelu(sib + a2b));
        float e3a = __expf(lrelu(sia + a3a)), e3b = __expf(lrelu(sib + a3b));
        dna += e0a + e1a + e2a + e3a;
        dnb += e0b + e1b + e2b + e3b;
        acc0 = fmaf(e0a, bf2f(m0a), acc0);
        acc1 = fmaf(e0b, bf2f(m0b), acc1);
        acc0 = fmaf(e1a, bf2f(m1a), acc0);
        acc1 = fmaf(e1b, bf2f(m1b), acc1);
        acc0 = fmaf(e2a, bf2f(m2a), acc0);
        acc1 = fmaf(e2b, bf2f(m2b), acc1);
        acc0 = fmaf(e3a, bf2f(m3a), acc0);
        acc1 = fmaf(e3b, bf2f(m3b), acc1);
    }
    for (; i < deg; ++i) {
        int s_ = cs[i];
        float aa = s_j[(size_t)s_ * 4 + g], ab = s_j[(size_t)s_ * 4 + 2 + g];
        unsigned short ma = log_xb[(size_t)s_ * 128 + lane];
        unsigned short mb = log_xb[(size_t)s_ * 128 + 64 + lane];
        float eA = __expf(lrelu(sia + aa)), eB = __expf(lrelu(sib + ab));
        dna += eA; dnb += eB;
        acc0 = fmaf(eA, bf2f(ma), acc0);
        acc1 = fmaf(eB, bf2f(mb), acc1);
    }

    // finalize: relu(num/den + bias) -> expmap0 -> proj (post-expmap norm analytic)
    float v0 = acc0 / fmaxf(dna, MIN_NORM) + conv_bias[lane];
    float v1 = acc1 / fmaxf(dnb, MIN_NORM) + conv_bias[lane + 64];
    v0 = fmaxf(v0, 0.f);
    v1 = fmaxf(v1, 0.f);
    float n2 = wave_reduce_sum(v0 * v0 + v1 * v1);
    float nn = fmaxf(sqrtf(n2), MIN_NORM);
    float tv = tanhf(nn);
    float s = tv / nn;
    float r0 = s * v0, r1 = s * v1;
    float rn = fmaxf(tv, MIN_NORM);
    if (rn > MAXNORM) { float f = MAXNORM / rn; r0 *= f; r1 *= f; }
    out[(size_t)n * 128 + lane] = r0;
    out[(size_t)n * 128 + 64 + lane] = r1;
}

extern "C" void kernel_launch(void* const* d_in, const int* in_sizes, int n_in,
                              void* d_out, int out_size, void* d_ws, size_t ws_size,
                              hipStream_t stream)
{
    const float* x        = (const float*)d_in[0];
    const float* W        = (const float*)d_in[1];
    const float* lin_bias = (const float*)d_in[2];
    const float* att      = (const float*)d_in[3];
    const float* conv_bias= (const float*)d_in[4];
    const int*   esrc     = (const int*)d_in[5];
    const int*   edst     = (const int*)d_in[6];
    int N = in_sizes[0] / 128;
    int E = in_sizes[5];
    float* out = (float*)d_out;
    int NCH = (N + 255) / 256;

    char* p = (char*)d_ws;
    float* bbuf   = (float*)p;  p += 256 * 4;
    unsigned short* whi = (unsigned short*)p; p += 16384 * 2;
    unsigned short* wlo = (unsigned short*)p; p += 16384 * 2;
    float* s_i    = (float*)p;  p += (size_t)N * 4 * 4;
    float* s_j    = (float*)p;  p += (size_t)N * 4 * 4;
    int*   cnt    = (int*)p;    p += (size_t)N * 4;
    int*   cursor = (int*)p;    p += (size_t)N * 4;
    int*   rowptr = (int*)p;    p += (size_t)(N + 1) * 4;
    int*   csum   = (int*)p;    p += 256 * 4;
    int*   coff   = (int*)p;    p += 256 * 4;
    int*   csr_src= (int*)p;    p += (size_t)E * 4;
    unsigned short* log_xb = (unsigned short*)p; p += (size_t)N * 128 * 2;

    hipMemsetAsync(cnt, 0, (size_t)N * 4, stream);

    prep_kernel<<<65, 256, 0, stream>>>(W, whi, wlo, lin_bias, bbuf);
    count_kernel<<<(E + 255) / 256, 256, 0, stream>>>(edst, E, cnt);
    chunksum_kernel<<<NCH, 256, 0, stream>>>(cnt, csum, N);
    chunkscan_kernel<<<1, 256, 0, stream>>>(csum, coff, rowptr, NCH, N);
    emit_kernel<<<NCH, 256, 0, stream>>>(cnt, coff, rowptr, cursor, N);
    fill_kernel<<<(E + 255) / 256, 256, 0, stream>>>(esrc, edst, E, cursor, csr_src);
    int nTiles = (N + 15) / 16;
    node_kernel<<<nTiles, 256, 0, stream>>>(x, whi, wlo, bbuf, att, log_xb, s_i, s_j, N);
    aggregate_kernel<<<(N * 64 + 255) / 256, 256, 0, stream>>>(
        rowptr, csr_src, s_i, s_j, log_xb, conv_bias, out, N);
}

// Round 7
// 134.622 us; speedup vs baseline: 5.7784x; 1.4374x over previous
//
#include <hip/hip_runtime.h>
#include <math.h>

#define EPSF 1e-7f
#define MIN_NORM 1e-15f
#define MAXNORM 0.996f   // (1 - 0.004)/sqrt(c), c=1
#define NEG_SLOPE 0.2f

typedef __attribute__((ext_vector_type(8))) short short8;
typedef __attribute__((ext_vector_type(4))) float f32x4;

__device__ __forceinline__ float wave_reduce_sum(float v) {
    #pragma unroll
    for (int m = 1; m < 64; m <<= 1) v += __shfl_xor(v, m, 64);
    return v;
}

__device__ __forceinline__ float artanhf_(float x) {
    x = fminf(fmaxf(x, -1.f + EPSF), 1.f - EPSF);
    return 0.5f * (log1pf(x) - log1pf(-x));
}

__device__ __forceinline__ float lrelu(float a) {
    return a < 0.f ? a * NEG_SLOPE : a;
}

// bf16 round-to-nearest-even (no NaN handling; inputs are tame)
__device__ __forceinline__ unsigned short f2bf(float f) {
    unsigned u = __float_as_uint(f);
    u += 0x7FFFu + ((u >> 16) & 1u);
    return (unsigned short)(u >> 16);
}
__device__ __forceinline__ float bf2f(unsigned short h) {
    return __uint_as_float(((unsigned)h) << 16);
}

// ---- K0: prep = wsplit (blocks 0..63) + hyp bias (block 64)
__global__ void prep_kernel(const float* __restrict__ W,
                            unsigned short* __restrict__ whi,
                            unsigned short* __restrict__ wlo,
                            const float* __restrict__ lin_bias,
                            float* __restrict__ bbuf) {
    if (blockIdx.x == 64) {
        if (threadIdx.x >= 64) return;
        int lane = threadIdx.x;
        float u0 = lin_bias[lane], u1 = lin_bias[lane + 64];
        float n2 = wave_reduce_sum(u0 * u0 + u1 * u1);
        float n = fmaxf(sqrtf(n2), MIN_NORM);
        float s = tanhf(n) / n;
        float b0 = s * u0, b1 = s * u1;
        float bn = fmaxf(tanhf(n), MIN_NORM);   // norm of expmap0 result, analytic
        float fn2 = bn * bn;
        if (bn > MAXNORM) { float f = MAXNORM / bn; b0 *= f; b1 *= f; fn2 = MAXNORM * MAXNORM; }
        bbuf[lane] = b0;
        bbuf[lane + 64] = b1;
        if (lane == 0) bbuf[128] = fn2;
        return;
    }
    int idx = blockIdx.x * 256 + threadIdx.x;   // 0..16383
    int i = idx & 7, l = (idx >> 3) & 63, ts = idx >> 9;
    int s = ts & 3, t = ts >> 2;
    int o = t * 16 + (l & 15);
    int k = s * 32 + ((l >> 4) * 8) + i;
    float f = W[o * 128 + k];
    unsigned short h = f2bf(f);
    unsigned short lo = f2bf(f - bf2f(h));
    whi[idx] = h;
    wlo[idx] = lo;
}

// ---- K1: per-node transform, MFMA matvec (bf16x3) + 16-lane-per-node chain.
#define DPAD 132   // 16B-aligned rows for float4 LDS reads
__global__ __launch_bounds__(256) void node_kernel(
    const float* __restrict__ x,
    const unsigned short* __restrict__ whi, const unsigned short* __restrict__ wlo,
    const float* __restrict__ bbuf, const float* __restrict__ att,
    unsigned short* __restrict__ log_xb,
    float* __restrict__ s_i, float* __restrict__ s_j, int N)
{
    __shared__ float mxs[16][DPAD];
    __shared__ float xn2s[16];
    int tid = threadIdx.x, wave = tid >> 6, lane = tid & 63;
    int nbase = blockIdx.x * 16;
    int arow = lane & 15, kgrp = lane >> 4;
    int anode = min(nbase + arow, N - 1);

    f32x4 acc0 = {0.f, 0.f, 0.f, 0.f};
    f32x4 acc1 = {0.f, 0.f, 0.f, 0.f};
    int t0 = wave * 2, t1 = wave * 2 + 1;
    float x2loc = 0.f;

    #pragma unroll
    for (int s = 0; s < 4; ++s) {
        const float* xp = x + (size_t)anode * 128 + s * 32 + kgrp * 8;
        float4 xa = *(const float4*)xp;
        float4 xb = *(const float4*)(xp + 4);
        float xv[8] = {xa.x, xa.y, xa.z, xa.w, xb.x, xb.y, xb.z, xb.w};
        short8 ahi, alo;
        #pragma unroll
        for (int i = 0; i < 8; ++i) {
            unsigned short h = f2bf(xv[i]);
            unsigned short l = f2bf(xv[i] - bf2f(h));
            ahi[i] = (short)h;
            alo[i] = (short)l;
        }
        if (wave == 0) {
            #pragma unroll
            for (int i = 0; i < 8; ++i) x2loc = fmaf(xv[i], xv[i], x2loc);
        }
        short8 bh0 = *(const short8*)(whi + ((size_t)(t0 * 4 + s) * 64 + lane) * 8);
        short8 bl0 = *(const short8*)(wlo + ((size_t)(t0 * 4 + s) * 64 + lane) * 8);
        short8 bh1 = *(const short8*)(whi + ((size_t)(t1 * 4 + s) * 64 + lane) * 8);
        short8 bl1 = *(const short8*)(wlo + ((size_t)(t1 * 4 + s) * 64 + lane) * 8);
        acc0 = __builtin_amdgcn_mfma_f32_16x16x32_bf16(ahi, bh0, acc0, 0, 0, 0);
        acc0 = __builtin_amdgcn_mfma_f32_16x16x32_bf16(alo, bh0, acc0, 0, 0, 0);
        acc0 = __builtin_amdgcn_mfma_f32_16x16x32_bf16(ahi, bl0, acc0, 0, 0, 0);
        acc1 = __builtin_amdgcn_mfma_f32_16x16x32_bf16(ahi, bh1, acc1, 0, 0, 0);
        acc1 = __builtin_amdgcn_mfma_f32_16x16x32_bf16(alo, bh1, acc1, 0, 0, 0);
        acc1 = __builtin_amdgcn_mfma_f32_16x16x32_bf16(ahi, bl1, acc1, 0, 0, 0);
    }
    if (wave == 0) {
        x2loc += __shfl_xor(x2loc, 16, 64);
        x2loc += __shfl_xor(x2loc, 32, 64);
        if (lane < 16) xn2s[lane] = x2loc;
    }
    #pragma unroll
    for (int r = 0; r < 4; ++r) {
        mxs[kgrp * 4 + r][t0 * 16 + arow] = acc0[r];
        mxs[kgrp * 4 + r][t1 * 16 + arow] = acc1[r];
    }
    __syncthreads();

    // ---- chain: 16 lanes per node, 8 dims per lane, 4 nodes per wave ----
    int g16 = lane >> 4, l16 = lane & 15;
    int nn = wave * 4 + g16;
    int node = nbase + nn;
    if (node < N) {
        int head = l16 >> 2;
        int dbase = l16 * 8;
        int dd8 = (l16 & 3) * 8;
        float bb[8], aiv[8], ajv[8];
        #pragma unroll
        for (int j = 0; j < 8; ++j) {
            bb[j] = bbuf[dbase + j];
            aiv[j] = att[head * 64 + dd8 + j];
            ajv[j] = att[head * 64 + 32 + dd8 + j];
        }
        float y2 = bbuf[128];

        float4 va = *(const float4*)&mxs[nn][dbase];
        float4 vb = *(const float4*)&mxs[nn][dbase + 4];
        float v[8] = {va.x, va.y, va.z, va.w, vb.x, vb.y, vb.z, vb.w};

        float mq = 0.f;
        #pragma unroll
        for (int j = 0; j < 8; ++j) mq = fmaf(v[j], v[j], mq);
        #pragma unroll
        for (int m = 1; m < 16; m <<= 1) mq += __shfl_xor(mq, m, 64);

        float xn2 = xn2s[nn];
        float xn = fmaxf(sqrtf(xn2), MIN_NORM);
        float mxn = fmaxf(sqrtf(mq), MIN_NORM);
        float t = tanhf(mxn / xn * artanhf_(xn));
        float scl = t / mxn;
        bool zero = (mq == 0.f);
        float r[8];
        #pragma unroll
        for (int j = 0; j < 8; ++j) r[j] = zero ? 0.f : scl * v[j];
        float rn2 = zero ? 0.f : t * t;
        float rn = zero ? MIN_NORM : fmaxf(fabsf(t), MIN_NORM);
        float x2 = rn2;
        if (rn > MAXNORM) {
            float f = MAXNORM / rn;
            #pragma unroll
            for (int j = 0; j < 8; ++j) r[j] *= f;
            x2 = MAXNORM * MAXNORM;
        }
        // mobius_add(r, bias)
        float xy = 0.f;
        #pragma unroll
        for (int j = 0; j < 8; ++j) xy = fmaf(r[j], bb[j], xy);
        #pragma unroll
        for (int m = 1; m < 16; m <<= 1) xy += __shfl_xor(xy, m, 64);
        float cA = 1.f + 2.f * xy + y2;
        float cB = 1.f - x2;
        float dn = fmaxf(1.f + 2.f * xy + x2 * y2, MIN_NORM);
        float inv = 1.f / dn;
        float h[8];
        #pragma unroll
        for (int j = 0; j < 8; ++j) h[j] = (cA * r[j] + cB * bb[j]) * inv;
        // proj + logmap0
        float hq = 0.f;
        #pragma unroll
        for (int j = 0; j < 8; ++j) hq = fmaf(h[j], h[j], hq);
        #pragma unroll
        for (int m = 1; m < 16; m <<= 1) hq += __shfl_xor(hq, m, 64);
        float hn = fmaxf(sqrtf(hq), MIN_NORM);
        float ln2 = hq;
        if (hn > MAXNORM) {
            float f = MAXNORM / hn;
            #pragma unroll
            for (int j = 0; j < 8; ++j) h[j] *= f;
            ln2 = MAXNORM * MAXNORM;
        }
        float lnn = fmaxf(sqrtf(ln2), MIN_NORM);
        float ls = artanhf_(lnn) / lnn;
        float lv[8];
        #pragma unroll
        for (int j = 0; j < 8; ++j) lv[j] = ls * h[j];
        uint4 pk;
        pk.x = (unsigned)f2bf(lv[0]) | ((unsigned)f2bf(lv[1]) << 16);
        pk.y = (unsigned)f2bf(lv[2]) | ((unsigned)f2bf(lv[3]) << 16);
        pk.z = (unsigned)f2bf(lv[4]) | ((unsigned)f2bf(lv[5]) << 16);
        pk.w = (unsigned)f2bf(lv[6]) | ((unsigned)f2bf(lv[7]) << 16);
        *(uint4*)&log_xb[(size_t)node * 128 + dbase] = pk;
        float pi = 0.f, pj = 0.f;
        #pragma unroll
        for (int j = 0; j < 8; ++j) {
            pi = fmaf(lv[j], aiv[j], pi);
            pj = fmaf(lv[j], ajv[j], pj);
        }
        pi += __shfl_xor(pi, 1, 64); pi += __shfl_xor(pi, 2, 64);
        pj += __shfl_xor(pj, 1, 64); pj += __shfl_xor(pj, 2, 64);
        if ((l16 & 3) == 0) {
            s_i[(size_t)node * 4 + head] = pi;
            s_j[(size_t)node * 4 + head] = pj;
        }
    }
}

// ---- K2: linked-list build: coalesced pair write + one atomicExch per edge.
// 16 chains per dst node; chain = e & 15.
__global__ void build_kernel(const int* __restrict__ src, const int* __restrict__ dst,
                             int E, int* __restrict__ head, int2* __restrict__ pair)
{
    int e = blockIdx.x * blockDim.x + threadIdx.x;
    if (e >= E) return;
    int s_ = src[e], d_ = dst[e];
    int prev = atomicExch(&head[(size_t)d_ * 16 + (e & 15)], e);
    pair[e] = make_int2(s_, prev);
}

// ---- K3: aggregate. One wave per node: chase 16 chains into LDS, then
// single-pass online softmax-aggregate + finalize (as R5).
#define MAXS 128
__global__ __launch_bounds__(256) void aggregate_kernel(
    const int* __restrict__ head, const int2* __restrict__ pair,
    const float* __restrict__ s_i, const float* __restrict__ s_j,
    const unsigned short* __restrict__ log_xb, const float* __restrict__ conv_bias,
    float* __restrict__ out, int N)
{
    __shared__ __align__(16) int slist[4][MAXS];
    __shared__ int scnt[4];
    int tid = threadIdx.x, wave = tid >> 6, lane = tid & 63;
    int n = blockIdx.x * 4 + wave;
    bool valid = n < N;

    if (lane == 0) scnt[wave] = 0;
    __syncthreads();

    int resume = -1;
    if (valid && lane < 16) {
        int e = head[(size_t)n * 16 + lane];
        while (e >= 0) {
            int2 pr = pair[e];          // (src, next)
            int pos = atomicAdd(&scnt[wave], 1);
            if (pos < MAXS) {
                slist[wave][pos] = pr.x;
                e = pr.y;
            } else { resume = e; break; }
        }
    }
    __syncthreads();

    int g = lane >> 5;                 // dim lane -> head g; dim lane+64 -> head 2+g
    float acc0 = 0.f, acc1 = 0.f, dna = 0.f, dnb = 0.f;
    float sia = 0.f, sib = 0.f;

#define EDGE_PROC(sid) do { \
    float aa_ = s_j[(size_t)(sid) * 4 + g], ab_ = s_j[(size_t)(sid) * 4 + 2 + g]; \
    float eA_ = __expf(lrelu(sia + aa_)), eB_ = __expf(lrelu(sib + ab_)); \
    dna += eA_; dnb += eB_; \
    acc0 = fmaf(eA_, bf2f(log_xb[(size_t)(sid) * 128 + lane]), acc0); \
    acc1 = fmaf(eB_, bf2f(log_xb[(size_t)(sid) * 128 + 64 + lane]), acc1); \
} while (0)

    int deg = 0;
    if (valid) {
        deg = min(scnt[wave], MAXS);
        float4 si = *(const float4*)(s_i + (size_t)n * 4);
        float4 sjn = *(const float4*)(s_j + (size_t)n * 4);
        sia = g == 0 ? si.x : si.y; sib = g == 0 ? si.z : si.w;
        float sjna = g == 0 ? sjn.x : sjn.y, sjnb = g == 0 ? sjn.z : sjn.w;

        // self-loop
        float ea = __expf(lrelu(sia + sjna));
        float eb = __expf(lrelu(sib + sjnb));
        dna = ea; dnb = eb;
        acc0 = ea * bf2f(log_xb[(size_t)n * 128 + lane]);
        acc1 = eb * bf2f(log_xb[(size_t)n * 128 + 64 + lane]);

        const int* sl = slist[wave];
        int i = 0;
        for (; i + 4 <= deg; i += 4) {
            int4 sq = *(const int4*)&sl[i];
            int s0 = sq.x, s1 = sq.y, s2 = sq.z, s3 = sq.w;
            float a0a = s_j[(size_t)s0 * 4 + g],     a0b = s_j[(size_t)s0 * 4 + 2 + g];
            float a1a = s_j[(size_t)s1 * 4 + g],     a1b = s_j[(size_t)s1 * 4 + 2 + g];
            float a2a = s_j[(size_t)s2 * 4 + g],     a2b = s_j[(size_t)s2 * 4 + 2 + g];
            float a3a = s_j[(size_t)s3 * 4 + g],     a3b = s_j[(size_t)s3 * 4 + 2 + g];
            unsigned short m0a = log_xb[(size_t)s0 * 128 + lane], m0b = log_xb[(size_t)s0 * 128 + 64 + lane];
            unsigned short m1a = log_xb[(size_t)s1 * 128 + lane], m1b = log_xb[(size_t)s1 * 128 + 64 + lane];
            unsigned short m2a = log_xb[(size_t)s2 * 128 + lane], m2b = log_xb[(size_t)s2 * 128 + 64 + lane];
            unsigned short m3a = log_xb[(size_t)s3 * 128 + lane], m3b = log_xb[(size_t)s3 * 128 + 64 + lane];
            float e0a = __expf(lrelu(sia + a0a)), e0b = __expf(lrelu(sib + a0b));
            float e1a = __expf(lrelu(sia + a1a)), e1b = __expf(lrelu(sib + a1b));
            float e2a = __expf(lrelu(sia + a2a)), e2b = __expf(lrelu(sib + a2b));
            float e3a = __expf(lrelu(sia + a3a)), e3b = __expf(lrelu(sib + a3b));
            dna += e0a + e1a + e2a + e3a;
            dnb += e0b + e1b + e2b + e3b;
            acc0 = fmaf(e0a, bf2f(m0a), acc0);
            acc1 = fmaf(e0b, bf2f(m0b), acc1);
            acc0 = fmaf(e1a, bf2f(m1a), acc0);
            acc1 = fmaf(e1b, bf2f(m1b), acc1);
            acc0 = fmaf(e2a, bf2f(m2a), acc0);
            acc1 = fmaf(e2b, bf2f(m2b), acc1);
            acc0 = fmaf(e3a, bf2f(m3a), acc0);
            acc1 = fmaf(e3b, bf2f(m3b), acc1);
        }
        for (; i < deg; ++i) {
            int s_ = sl[i];
            EDGE_PROC(s_);
        }
    }

    // cold path: chains that overflowed the LDS list (practically never)
    unsigned long long mask = __ballot(resume >= 0);
    while (mask) {
        int l = __ffsll((long long)mask) - 1;
        int e = __shfl(resume, l, 64);
        while (e >= 0) {
            int sv = 0, nx = -1;
            if (lane == 0) { int2 pr = pair[e]; sv = pr.x; nx = pr.y; }
            sv = __shfl(sv, 0, 64);
            e = __shfl(nx, 0, 64);
            EDGE_PROC(sv);
        }
        mask &= mask - 1;
    }
#undef EDGE_PROC

    if (!valid) return;

    // finalize: relu(num/den + bias) -> expmap0 -> proj (post-expmap norm analytic)
    float v0 = acc0 / fmaxf(dna, MIN_NORM) + conv_bias[lane];
    float v1 = acc1 / fmaxf(dnb, MIN_NORM) + conv_bias[lane + 64];
    v0 = fmaxf(v0, 0.f);
    v1 = fmaxf(v1, 0.f);
    float n2 = wave_reduce_sum(v0 * v0 + v1 * v1);
    float nn = fmaxf(sqrtf(n2), MIN_NORM);
    float tv = tanhf(nn);
    float s = tv / nn;
    float r0 = s * v0, r1 = s * v1;
    float rn = fmaxf(tv, MIN_NORM);
    if (rn > MAXNORM) { float f = MAXNORM / rn; r0 *= f; r1 *= f; }
    out[(size_t)n * 128 + lane] = r0;
    out[(size_t)n * 128 + 64 + lane] = r1;
}

extern "C" void kernel_launch(void* const* d_in, const int* in_sizes, int n_in,
                              void* d_out, int out_size, void* d_ws, size_t ws_size,
                              hipStream_t stream)
{
    const float* x        = (const float*)d_in[0];
    const float* W        = (const float*)d_in[1];
    const float* lin_bias = (const float*)d_in[2];
    const float* att      = (const float*)d_in[3];
    const float* conv_bias= (const float*)d_in[4];
    const int*   esrc     = (const int*)d_in[5];
    const int*   edst     = (const int*)d_in[6];
    int N = in_sizes[0] / 128;
    int E = in_sizes[5];
    float* out = (float*)d_out;

    char* p = (char*)d_ws;
    float* bbuf   = (float*)p;  p += 256 * 4;
    unsigned short* whi = (unsigned short*)p; p += 16384 * 2;
    unsigned short* wlo = (unsigned short*)p; p += 16384 * 2;
    float* s_i    = (float*)p;  p += (size_t)N * 4 * 4;
    float* s_j    = (float*)p;  p += (size_t)N * 4 * 4;
    int*   head   = (int*)p;    p += (size_t)N * 16 * 4;
    int2*  pair   = (int2*)p;   p += (size_t)E * 8;
    unsigned short* log_xb = (unsigned short*)p; p += (size_t)N * 128 * 2;

    hipMemsetAsync(head, 0xFF, (size_t)N * 16 * 4, stream);   // head = -1

    prep_kernel<<<65, 256, 0, stream>>>(W, whi, wlo, lin_bias, bbuf);
    build_kernel<<<(E + 255) / 256, 256, 0, stream>>>(esrc, edst, E, head, pair);
    int nTiles = (N + 15) / 16;
    node_kernel<<<nTiles, 256, 0, stream>>>(x, whi, wlo, bbuf, att, log_xb, s_i, s_j, N);
    aggregate_kernel<<<(N + 3) / 4, 256, 0, stream>>>(
        head, pair, s_i, s_j, log_xb, conv_bias, out, N);
}